// Round 6
// baseline (309.018 us; speedup 1.0000x reference)
//
#include <hip/hip_runtime.h>
#include <math.h>

// Problem constants (fixed by reference)
static constexpr int NN = 50000;   // nodes
static constexpr int EE = 400000;  // edges (without self loops)
static constexpr int GG = 2048;    // graphs
static constexpr int TASKS = 12;

typedef __attribute__((ext_vector_type(8))) short short8;   // 8 bf16 (4 VGPRs)
typedef __attribute__((ext_vector_type(4))) float floatx4;  // MFMA acc

__device__ __forceinline__ unsigned short f2bf(float f) {
  unsigned u = __float_as_uint(f);
  u = u + 0x7fffu + ((u >> 16) & 1u);  // RNE
  return (unsigned short)(u >> 16);
}
__device__ __forceinline__ float bflo(unsigned u) { return __uint_as_float(u << 16); }
__device__ __forceinline__ float bfhi(unsigned u) { return __uint_as_float(u & 0xffff0000u); }

// ---------------------------------------------------------------------------
// Fused independent preamble, grid-partitioned:
//   [0,NBDEG)       in-degree histogram (distributed atomics — safe)
//   [+NBMEAN)       edge_attr mean sums (LDS pre-reduce, 6 atomics/blk — R5 lesson)
//   [+NBX)          x -> bf16 [NN][32] zero-padded (8 outputs/thread)
//   [+NW1)          W1 -> bf16 fragment-tiled [row>>4][kc][row&15][8], K=32
//   [+NW2)          W2 -> bf16 fragment-tiled [row>>4][kc][row&15][8], K=256
// Tiled layout makes each GEMM B-fragment load a contiguous 1KB wave burst
// (R9's B^T row-major gave 16 scattered 64B requests per load instr).
static constexpr int NBDEG = (EE + 255) / 256;     // 1563
static constexpr int NBMEAN = 256;
static constexpr int NBX = (NN * 4 + 255) / 256;   // 782 (thread = 8 bf16 outs)
static constexpr int NW1 = 32;
static constexpr int NW2 = 256;
__global__ void k_pre(const int* __restrict__ dst, const float* __restrict__ ea,
                      const float* __restrict__ x, const float* __restrict__ W1,
                      const float* __restrict__ W2, int* __restrict__ deg,
                      float* __restrict__ msum, unsigned short* __restrict__ xb,
                      unsigned short* __restrict__ w1t, unsigned short* __restrict__ w2t) {
  const int b = blockIdx.x;
  const int t = threadIdx.x;
  if (b < NBDEG) {
    int e = b * 256 + t;
    if (e < EE) atomicAdd(&deg[dst[e]], 1);
  } else if (b < NBDEG + NBMEAN) {
    float s[6] = {0, 0, 0, 0, 0, 0};
    for (int e = (b - NBDEG) * 256 + t; e < EE; e += NBMEAN * 256) {
#pragma unroll
      for (int d = 0; d < 6; d++) s[d] += ea[(size_t)e * 6 + d];
    }
    __shared__ float ls[6];
    if (t < 6) ls[t] = 0.f;
    __syncthreads();
#pragma unroll
    for (int d = 0; d < 6; d++) atomicAdd(&ls[d], s[d]);
    __syncthreads();
    if (t < 6) atomicAdd(&msum[t], ls[t]);
  } else if (b < NBDEG + NBMEAN + NBX) {
    int i = (b - NBDEG - NBMEAN) * 256 + t;  // i indexes 8-element chunks
    if (i < NN * 4) {
      int n = i >> 2, seg = i & 3;
      unsigned short v[8];
#pragma unroll
      for (int j = 0; j < 8; j++) {
        int k = seg * 8 + j;
        v[j] = (k < 29) ? f2bf(x[(size_t)n * 29 + k]) : (unsigned short)0;
      }
      *(short8*)(xb + (size_t)n * 32 + seg * 8) = *(short8*)v;
    }
  } else if (b < NBDEG + NBMEAN + NBX + NW1) {
    int i = (b - NBDEG - NBMEAN - NBX) * 256 + t;  // 8192 elems
    int row = i >> 5, k = i & 31;
    unsigned short v = (k < 29) ? f2bf(W1[(size_t)k * 256 + row]) : (unsigned short)0;
    w1t[((row >> 4) * 4 + (k >> 3)) * 128 + (row & 15) * 8 + (k & 7)] = v;
  } else {
    int i = (b - NBDEG - NBMEAN - NBX - NW1) * 256 + t;  // 65536 elems
    int row = i >> 8, k = i & 255;
    w2t[((row >> 4) * 32 + (k >> 3)) * 128 + (row & 15) * 8 + (k & 7)] = f2bf(W2[(size_t)k * 256 + row]);
  }
}

static constexpr int NBS = (NN + 255) / 256;  // 196 scan blocks

// block-level exclusive scan of deg -> rowptr (partial), block totals -> bsums.
// +2 trailing blocks compute per-layer edge params p1/p2.
__global__ void k_scan1(const int* __restrict__ deg, int* __restrict__ rowptr,
                        int* __restrict__ bsums, const float* __restrict__ We1,
                        const float* __restrict__ ae1, const float* __restrict__ We2,
                        const float* __restrict__ ae2, const float* __restrict__ msum,
                        float* __restrict__ p1, float* __restrict__ p2) {
  const int t = threadIdx.x;
  if (blockIdx.x >= NBS) {
    const int layer = blockIdx.x - NBS;
    const float* We = layer ? We2 : We1;
    const float* ae = layer ? ae2 : ae1;
    float* params = layer ? p2 : p1;
    __shared__ float vsh[24];
    if (t < 24) {
      int d = t >> 2, h = t & 3;
      float s = 0.f;
      for (int c = 0; c < 64; c++) s += We[d * 256 + h * 64 + c] * ae[h * 64 + c];
      vsh[t] = s;
      params[t] = s;
    }
    __syncthreads();
    if (t < 4) {
      float s = 0.f;
      const float invE = 1.0f / (float)EE;
#pragma unroll
      for (int d = 0; d < 6; d++) s += (msum[d] * invE) * vsh[d * 4 + t];
      params[24 + t] = s;
    }
    return;
  }
  __shared__ int sh[256];
  int i = blockIdx.x * 256 + t;
  int v = (i < NN) ? deg[i] : 0;
  sh[t] = v;
  __syncthreads();
  for (int off = 1; off < 256; off <<= 1) {
    int tv = (t >= off) ? sh[t - off] : 0;
    __syncthreads();
    sh[t] += tv;
    __syncthreads();
  }
  if (i < NN) rowptr[i] = sh[t] - v;  // exclusive within block
  if (t == 255) bsums[blockIdx.x] = sh[255];
}

// fused scan2+scan3: every block redundantly scans the 196 block sums,
// then applies its own block's exclusive prefix to rowptr.
__global__ void k_scan23(int* __restrict__ rowptr, const int* __restrict__ bsums, int nb) {
  __shared__ int sh[256];
  const int t = threadIdx.x;
  sh[t] = (t < nb) ? bsums[t] : 0;
  __syncthreads();
  for (int off = 1; off < 256; off <<= 1) {
    int tv = (t >= off) ? sh[t - off] : 0;
    __syncthreads();
    sh[t] += tv;  // inclusive scan
    __syncthreads();
  }
  const int add = (blockIdx.x == 0) ? 0 : sh[blockIdx.x - 1];
  int i = blockIdx.x * 256 + t;
  if (i < NN) rowptr[i] += add;
  if (i == 0) rowptr[NN] = EE;
}

// ---------------------------------------------------------------------------
// GEMM body (device fn): Y[M,256](bf16) = A[M,KP](bf16 row-major) @ B(tiled)
// + fused per-head logits. BM=64; 4 waves; wave w owns cols [64w,64w+64) = head w.
//
// R12: A tile staged in LDS, XOR-swizzled (one coalesced 4/32KB block read ->
// swizzled ds_write_b128; conflict-free ds_read_b128 frags).
//   swizzle f(o) = o ^ ((row(o)&7)<<4), row(o)=o/(2KP), same map write & read.
// R13: B register prefetch distance 2 (3 rolling buffers) + A frag LDS->reg
// prefetch distance 1.
template <int KP>
__device__ __forceinline__ void gemm_body(
    int bx, const unsigned short* __restrict__ A, const unsigned short* __restrict__ Bt,
    const float* __restrict__ a_s, const float* __restrict__ a_d,
    unsigned short* __restrict__ Y, float* __restrict__ als, float* __restrict__ ald, int M) {
  __shared__ __align__(16) unsigned short Ash[64 * KP];
  const int tid = threadIdx.x;
  const int lane = tid & 63;
  const int w = tid >> 6;
  const int l15 = lane & 15;
  const int quad = lane >> 4;
  const int row0 = bx * 64;

  // ---- stage A tile: coalesced global read (may read a few KB past the end
  // of A for the last block — lands in adjacent workspace buffers, harmless;
  // all outputs are row<M guarded) -> swizzled LDS write ----
  constexpr int STEPS = (64 * KP * 2) / (256 * 16);  // 1 (KP=32) or 8 (KP=256)
  {
    const char* Ab = (const char*)(A + (size_t)row0 * KP);
    uint4 stg[STEPS];
#pragma unroll
    for (int s = 0; s < STEPS; s++) stg[s] = *(const uint4*)(Ab + s * 4096 + tid * 16);
#pragma unroll
    for (int s = 0; s < STEPS; s++) {
      int o = s * 4096 + tid * 16;
      int row = o / (KP * 2);
      *(uint4*)((char*)Ash + (o ^ ((row & 7) << 4))) = stg[s];
    }
  }

  floatx4 acc[4][4];
#pragma unroll
  for (int i = 0; i < 4; i++)
#pragma unroll
    for (int j = 0; j < 4; j++) acc[i][j] = {0.f, 0.f, 0.f, 0.f};

  const unsigned short* pb[4];
#pragma unroll
  for (int j = 0; j < 4; j++)
    pb[j] = Bt + (size_t)((w * 4 + j) * (KP / 8) + quad) * 128 + l15 * 8;

  constexpr int NPH = KP / 32;
  short8 bfr[3][4];
#pragma unroll
  for (int j = 0; j < 4; j++) bfr[0][j] = *(const short8*)pb[j];  // overlaps staging
  if (NPH > 1) {
#pragma unroll
    for (int j = 0; j < 4; j++) {
      pb[j] += 512;  // 4 kc * 128
      bfr[1][j] = *(const short8*)pb[j];
    }
  }

  __syncthreads();

  // A fragment loader: conflict-free swizzled ds_read_b128 (row&7 == l15&7)
  auto ldA = [&](int ph, short8 (&dst)[4]) {
#pragma unroll
    for (int i = 0; i < 4; i++) {
      int lin = (i * 16 + l15) * (KP * 2) + ph * 64 + quad * 16;
      dst[i] = *(const short8*)((const char*)Ash + (lin ^ ((l15 & 7) << 4)));
    }
  };
  short8 af[2][4];
  ldA(0, af[0]);

#pragma unroll
  for (int ph = 0; ph < NPH; ph++) {
    if (ph + 2 < NPH) {  // B prefetch two phases ahead
#pragma unroll
      for (int j = 0; j < 4; j++) {
        pb[j] += 512;
        bfr[(ph + 2) % 3][j] = *(const short8*)pb[j];
      }
    }
    if (ph + 1 < NPH) ldA(ph + 1, af[(ph + 1) & 1]);  // A frag one ahead
#pragma unroll
    for (int i = 0; i < 4; i++)
#pragma unroll
      for (int j = 0; j < 4; j++)
        acc[i][j] = __builtin_amdgcn_mfma_f32_16x16x32_bf16(af[ph & 1][i], bfr[ph % 3][j], acc[i][j], 0, 0, 0);
  }
  // epilogue: C/D layout (m89) col = lane&15, row = (lane>>4)*4 + reg.
  float asc[4], adc[4];
#pragma unroll
  for (int j = 0; j < 4; j++) {
    asc[j] = a_s[w * 64 + j * 16 + l15];
    adc[j] = a_d[w * 64 + j * 16 + l15];
  }
#pragma unroll
  for (int i = 0; i < 4; i++) {
#pragma unroll
    for (int r = 0; r < 4; r++) {
      const int row = row0 + i * 16 + quad * 4 + r;
      unsigned ub[4];
      float hv[4];
#pragma unroll
      for (int j = 0; j < 4; j++) {
        ub[j] = f2bf(acc[i][j][r]);
        hv[j] = __uint_as_float(ub[j] << 16);  // dot uses rounded value (matches agg reads)
      }
      if (row < M) {
#pragma unroll
        for (int j = 0; j < 4; j++) Y[(size_t)row * 256 + w * 64 + j * 16 + l15] = (unsigned short)ub[j];
      }
      float ps = hv[0] * asc[0] + hv[1] * asc[1] + hv[2] * asc[2] + hv[3] * asc[3];
      float pd = hv[0] * adc[0] + hv[1] * adc[1] + hv[2] * adc[2] + hv[3] * adc[3];
#pragma unroll
      for (int off = 1; off < 16; off <<= 1) {
        ps += __shfl_xor(ps, off, 64);
        pd += __shfl_xor(pd, off, 64);
      }
      if (l15 == 0 && row < M) {
        als[row * 4 + w] = ps;
        ald[row * 4 + w] = pd;
      }
    }
  }
}

static constexpr int GB = (NN + 63) / 64;  // 782 GEMM blocks

// slot-ordered edc helper: gather ea row by edge id, project onto per-layer
// edge params, write SEQUENTIALLY in slot order (full lines).
__device__ __forceinline__ void edc_body(int slot, const int2* __restrict__ cse,
                                         const float* __restrict__ ea,
                                         const float* __restrict__ p, float* __restrict__ ed) {
  int e = cse[slot].y;
  const float* ep = ea + (size_t)e * 6;
  float2 e0 = *(const float2*)ep;
  float2 e1 = *(const float2*)(ep + 2);
  float2 e2 = *(const float2*)(ep + 4);
  float c[4];
#pragma unroll
  for (int h = 0; h < 4; h++) {
    c[h] = e0.x * p[0 * 4 + h] + e0.y * p[1 * 4 + h] + e1.x * p[2 * 4 + h] +
           e1.y * p[3 * 4 + h] + e2.x * p[4 * 4 + h] + e2.y * p[5 * 4 + h];
  }
  *(float4*)(ed + (size_t)slot * 4) = make_float4(c[0], c[1], c[2], c[3]);
}

// Fused: CSR scatter (1563 blks) ∥ layer-1 GEMM (782 blks).
// R14: scatter writes ONE 8B record {src, edge_id} per slot (R13's scattered
// float4 logit writes were 80MB of partial-line HBM evictions at 1.9TB/s).
__global__ __launch_bounds__(256, 2) void k_scatgemm1(
    const int* __restrict__ ei, const int* __restrict__ rowptr, int* __restrict__ cursor,
    int2* __restrict__ cse,
    const unsigned short* __restrict__ xb, const unsigned short* __restrict__ w1t,
    const float* __restrict__ as1, const float* __restrict__ ad1,
    unsigned short* __restrict__ hb, float* __restrict__ als, float* __restrict__ ald) {
  const int b = blockIdx.x;
  const int t = threadIdx.x;
  if (b < NBDEG) {
    int e = b * 256 + t;
    if (e >= EE) return;
    int s = ei[e];
    int d = ei[EE + e];
    int p = atomicAdd(&cursor[d], 1);
    int slot = rowptr[d] + p;
    cse[slot] = make_int2(s, e);
  } else {
    gemm_body<32>(b - NBDEG, xb, w1t, as1, ad1, hb, als, ald, NN);
  }
}

// R16: layer-1 edc only (~half of R15's k_edc — the ed2 half rides in
// k_gemm2's grid where it overlaps latency-bound GEMM blocks for free).
__global__ void k_edc(const int2* __restrict__ cse, const float* __restrict__ ea,
                      const float* __restrict__ p1, float* __restrict__ ed1) {
  int slot = blockIdx.x * 256 + threadIdx.x;
  if (slot < EE) edc_body(slot, cse, ea, p1, ed1);
}

// layer-2 GEMM ∥ layer-2 edc (extra NBDEG partition blocks — R16).
__global__ __launch_bounds__(256, 2) void k_gemm2(
    const unsigned short* __restrict__ A, const unsigned short* __restrict__ Bt,
    const float* __restrict__ a_s, const float* __restrict__ a_d,
    unsigned short* __restrict__ Y, float* __restrict__ als, float* __restrict__ ald,
    const int2* __restrict__ cse, const float* __restrict__ ea,
    const float* __restrict__ p2, float* __restrict__ ed2) {
  if (blockIdx.x < GB) {
    gemm_body<256>(blockIdx.x, A, Bt, a_s, a_d, Y, als, ald, NN);
  } else {
    int slot = (blockIdx.x - GB) * 256 + threadIdx.x;
    if (slot < EE) edc_body(slot, cse, ea, p2, ed2);
  }
}

__device__ __forceinline__ float leaky02(float x) { return x > 0.f ? x : 0.2f * x; }

// GAT aggregation on bf16 h, one wave per node, halves of the wave own even/odd
// CSR slots; chunked 4-deep gather (4 independent 512B row gathers in flight
// per half-wave; chunk-tail guards are half-wave-uniform -> exec-masked).
// R15: edc read as slot-ordered stream. R16: PERSISTENT grid-stride waves —
// the 12500 one-node blocks showed OccupancyPercent 40% (VGPR=44 allows 8
// blocks/CU; tiny blocks churned dispatch/drain). Now 2048 blocks = 8/CU
// resident, each wave loops nodes at stride 8192; uniform bias/params hoisted.
// Logits are O(1) (0.1-scaled weights) so no max-subtraction; exp can't overflow.
// out = (Σ ex·h[src] + ex_self·h[n]) / Σ ex, +b, relu -> bf16.
static constexpr int NAB = 2048;  // agg blocks (8 waves-worth of 256thr each)
__global__ __launch_bounds__(256) void k_agg(
    const unsigned short* __restrict__ hinb, const float* __restrict__ als,
    const float* __restrict__ ald, const int* __restrict__ rowptr, const int2* __restrict__ cse,
    const float* __restrict__ edc, const float* __restrict__ params, const float* __restrict__ bias,
    unsigned short* __restrict__ houtb) {
  const int lane = threadIdx.x & 63;
  const int wid = blockIdx.x * 4 + (threadIdx.x >> 6);  // global wave id
  const int half = lane >> 5;  // 0: even slots, 1: odd slots
  const int sl = lane & 31;    // 16B chunk (8 channels) within row
  const int head = sl >> 3;

  // uniform-per-wave hoists
  const float selfp = params[24 + head];
  float4 b0 = *(const float4*)(bias + sl * 8);
  float4 b1 = *(const float4*)(bias + sl * 8 + 4);
  const float bb[8] = {b0.x, b0.y, b0.z, b0.w, b1.x, b1.y, b1.z, b1.w};

  for (int n = wid; n < NN; n += NAB * 4) {
    const float aldn = ald[n * 4 + head];
    float acc[8];
    float ssum;
    {
      float slg = leaky02(als[n * 4 + head] + aldn + selfp);
      float exs = __expf(slg);
      float wgt = (half == 0) ? exs : 0.f;  // self term counted once (cross-half merge later)
      ssum = wgt;
      uint4 uv = *(const uint4*)(hinb + (size_t)n * 256 + sl * 8);
      acc[0] = bflo(uv.x) * wgt;
      acc[1] = bfhi(uv.x) * wgt;
      acc[2] = bflo(uv.y) * wgt;
      acc[3] = bfhi(uv.y) * wgt;
      acc[4] = bflo(uv.z) * wgt;
      acc[5] = bfhi(uv.z) * wgt;
      acc[6] = bflo(uv.w) * wgt;
      acc[7] = bfhi(uv.w) * wgt;
    }
    const int end = rowptr[n + 1];
    int s = rowptr[n] + half;
    while (s < end) {
      int sid[4];
      float edv[4];
      // meta for 4 slots (sequential within the node's CSR range — L1/L2 hits)
#pragma unroll
      for (int k = 0; k < 4; k++) {
        const int q = s + 2 * k;
        const bool v = q < end;           // uniform across the 32-lane half
        const int idx = v ? q : end - 1;  // clamped: valid address
        sid[k] = cse[idx].x;
        edv[k] = v ? edc[(size_t)idx * 4 + head] : 0.f;
      }
      // src-logit + h-row gathers, all in flight together
      float alv[4];
#pragma unroll
      for (int k = 0; k < 4; k++) alv[k] = als[(size_t)sid[k] * 4 + head];
      uint4 r[4];
#pragma unroll
      for (int k = 0; k < 4; k++) {
        r[k] = make_uint4(0u, 0u, 0u, 0u);
        if (s + 2 * k < end) r[k] = *(const uint4*)(hinb + (size_t)sid[k] * 256 + sl * 8);
      }
#pragma unroll
      for (int k = 0; k < 4; k++) {
        const float ex = (s + 2 * k < end) ? __expf(leaky02(alv[k] + aldn + edv[k])) : 0.f;
        acc[0] += bflo(r[k].x) * ex;
        acc[1] += bfhi(r[k].x) * ex;
        acc[2] += bflo(r[k].y) * ex;
        acc[3] += bfhi(r[k].y) * ex;
        acc[4] += bflo(r[k].z) * ex;
        acc[5] += bfhi(r[k].z) * ex;
        acc[6] += bflo(r[k].w) * ex;
        acc[7] += bfhi(r[k].w) * ex;
        ssum += ex;
      }
      s += 8;  // 4 slots per half per chunk
    }
    // merge even/odd halves (same channel set lives at lane and lane^32)
#pragma unroll
    for (int j = 0; j < 8; j++) acc[j] += __shfl_xor(acc[j], 32, 64);
    ssum += __shfl_xor(ssum, 32, 64);
    if (half == 0) {
      const float inv = 1.f / (ssum + 1e-16f);
      uint p[4];
#pragma unroll
      for (int j = 0; j < 4; j++) {
        float e0 = fmaxf(acc[2 * j] * inv + bb[2 * j], 0.f);
        float e1 = fmaxf(acc[2 * j + 1] * inv + bb[2 * j + 1], 0.f);
        p[j] = (uint)f2bf(e0) | ((uint)f2bf(e1) << 16);
      }
      *(uint4*)(houtb + (size_t)n * 256 + sl * 8) = make_uint4(p[0], p[1], p[2], p[3]);
    }
  }
}

// per-graph mean pool (bf16 in) + readout linear (256->12).
// Node range split across both 128-lane halves (R10 idled threads 128-255).
__global__ __launch_bounds__(256) void k_pool(const unsigned short* __restrict__ hb,
                                              const int* __restrict__ batch,
                                              const float* __restrict__ Wl,
                                              const float* __restrict__ bl,
                                              float* __restrict__ out) {
  int g = blockIdx.x;
  int t = threadIdx.x;
  int lo = 0, hi = NN;
  while (lo < hi) {
    int mid = (lo + hi) >> 1;
    if (batch[mid] < g) lo = mid + 1; else hi = mid;
  }
  int start = lo;
  hi = NN;
  while (lo < hi) {
    int mid = (lo + hi) >> 1;
    if (batch[mid] < g + 1) lo = mid + 1; else hi = mid;
  }
  int end = lo;
  const int mid2 = start + ((end - start) >> 1);
  __shared__ float sp[256], sq[256];
  {
    const int c = t & 127;
    const int hseg = t >> 7;  // 0: [start,mid2), 1: [mid2,end)
    const int a = hseg ? mid2 : start;
    const int b = hseg ? end : mid2;
    float s0 = 0.f, s1 = 0.f;
    for (int n2 = a; n2 < b; n2++) {
      uint u = ((const uint*)(hb + (size_t)n2 * 256))[c];
      s0 += bflo(u);
      s1 += bfhi(u);
    }
    float* dst = hseg ? sq : sp;
    dst[2 * c] = s0;
    dst[2 * c + 1] = s1;
  }
  __syncthreads();
  if (t < TASKS) {
    float invc = 1.f / fmaxf((float)(end - start), 1.f);
    float o = bl[t];
    for (int c = 0; c < 256; c++) o += (sp[c] + sq[c]) * invc * Wl[c * 12 + t];
    out[(size_t)g * 12 + t] = o;
  }
}

// ---------------------------------------------------------------------------
extern "C" void kernel_launch(void* const* d_in, const int* in_sizes, int n_in,
                              void* d_out, int out_size, void* d_ws, size_t ws_size,
                              hipStream_t stream) {
  const float* x = (const float*)d_in[0];
  const int* ei = (const int*)d_in[1];
  const float* ea = (const float*)d_in[2];
  const int* batch = (const int*)d_in[3];
  const float* W1 = (const float*)d_in[4];
  const float* as1 = (const float*)d_in[5];
  const float* ad1 = (const float*)d_in[6];
  const float* We1 = (const float*)d_in[7];
  const float* ae1 = (const float*)d_in[8];
  const float* b1 = (const float*)d_in[9];
  const float* W2 = (const float*)d_in[10];
  const float* as2 = (const float*)d_in[11];
  const float* ad2 = (const float*)d_in[12];
  const float* We2 = (const float*)d_in[13];
  const float* ae2 = (const float*)d_in[14];
  const float* b2 = (const float*)d_in[15];
  const float* Wl = (const float*)d_in[16];
  const float* bl = (const float*)d_in[17];
  float* out = (float*)d_out;

  // workspace carve-up (256B aligned)
  char* ws = (char*)d_ws;
  size_t off = 0;
  auto take = [&](size_t bytes) -> char* {
    char* p = ws + off;
    off = (off + bytes + 255) & ~(size_t)255;
    return p;
  };
  float* msum = (float*)take(8 * 4);
  int* deg = (int*)take((size_t)NN * 4);
  int* cursor = (int*)take((size_t)NN * 4);
  size_t zero_end = off;  // msum+deg+cursor need zeroing
  int* rowptr = (int*)take((size_t)(NN + 1) * 4);
  int* bsums = (int*)take(256 * 4);
  int2* cse = (int2*)take((size_t)EE * 8);
  float* ed1 = (float*)take((size_t)EE * 4 * 4);
  float* ed2 = (float*)take((size_t)EE * 4 * 4);
  float* p1 = (float*)take(32 * 4);
  float* p2 = (float*)take(32 * 4);
  float* als = (float*)take((size_t)NN * 4 * 4);
  float* ald = (float*)take((size_t)NN * 4 * 4);
  unsigned short* hb = (unsigned short*)take((size_t)NN * 256 * 2);  // GEMM out (bf16)
  unsigned short* ab = (unsigned short*)take((size_t)NN * 256 * 2);  // agg out (bf16)
  unsigned short* xb = (unsigned short*)take((size_t)NN * 32 * 2);
  unsigned short* w1t = (unsigned short*)take((size_t)256 * 32 * 2);
  unsigned short* w2t = (unsigned short*)take((size_t)256 * 256 * 2);
  (void)ws_size;

  hipMemsetAsync(ws, 0, zero_end, stream);

  k_pre<<<NBDEG + NBMEAN + NBX + NW1 + NW2, 256, 0, stream>>>(ei + EE, ea, x, W1, W2,
                                                              deg, msum, xb, w1t, w2t);
  k_scan1<<<NBS + 2, 256, 0, stream>>>(deg, rowptr, bsums, We1, ae1, We2, ae2, msum, p1, p2);
  k_scan23<<<NBS, 256, 0, stream>>>(rowptr, bsums, NBS);

  // CSR scatter ∥ layer-1 GEMM (independent partitions)
  k_scatgemm1<<<NBDEG + GB, 256, 0, stream>>>(ei, rowptr, cursor, cse,
                                              xb, w1t, as1, ad1, hb, als, ald);

  // slot-ordered edc for layer 1 (stream writes; ea gathered once)
  k_edc<<<NBDEG, 256, 0, stream>>>(cse, ea, p1, ed1);

  // Layer 1 (cont.)
  k_agg<<<NAB, 256, 0, stream>>>(hb, als, ald, rowptr, cse, ed1, p1, b1, ab);

  // Layer 2 (GEMM ∥ ed2 partition)
  k_gemm2<<<GB + NBDEG, 256, 0, stream>>>(ab, w2t, as2, ad2, hb, als, ald,
                                          cse, ea, p2, ed2);
  k_agg<<<NAB, 256, 0, stream>>>(hb, als, ald, rowptr, cse, ed2, p2, b2, ab);

  // Pool + readout
  k_pool<<<GG, 256, 0, stream>>>(ab, batch, Wl, bl, out);
}

// Round 7
// 295.433 us; speedup vs baseline: 1.0460x; 1.0460x over previous
//
#include <hip/hip_runtime.h>
#include <math.h>

// Problem constants (fixed by reference)
static constexpr int NN = 50000;   // nodes
static constexpr int EE = 400000;  // edges (without self loops)
static constexpr int GG = 2048;    // graphs
static constexpr int TASKS = 12;

typedef __attribute__((ext_vector_type(8))) short short8;   // 8 bf16 (4 VGPRs)
typedef __attribute__((ext_vector_type(4))) float floatx4;  // MFMA acc

__device__ __forceinline__ unsigned short f2bf(float f) {
  unsigned u = __float_as_uint(f);
  u = u + 0x7fffu + ((u >> 16) & 1u);  // RNE
  return (unsigned short)(u >> 16);
}
__device__ __forceinline__ float bflo(unsigned u) { return __uint_as_float(u << 16); }
__device__ __forceinline__ float bfhi(unsigned u) { return __uint_as_float(u & 0xffff0000u); }

// ---------------------------------------------------------------------------
// Fused independent preamble, grid-partitioned:
//   [0,NBDEG)       in-degree histogram (distributed atomics — safe)
//   [+NBMEAN)       edge_attr mean sums (LDS pre-reduce, 6 atomics/blk — R5 lesson)
//   [+NBX)          x -> bf16 [NN][32] zero-padded (8 outputs/thread)
//   [+NW1)          W1 -> bf16 fragment-tiled [row>>4][kc][row&15][8], K=32
//   [+NW2)          W2 -> bf16 fragment-tiled [row>>4][kc][row&15][8], K=256
// Tiled layout makes each GEMM B-fragment load a contiguous 1KB wave burst
// (R9's B^T row-major gave 16 scattered 64B requests per load instr).
static constexpr int NBDEG = (EE + 255) / 256;     // 1563
static constexpr int NBMEAN = 256;
static constexpr int NBX = (NN * 4 + 255) / 256;   // 782 (thread = 8 bf16 outs)
static constexpr int NW1 = 32;
static constexpr int NW2 = 256;
__global__ void k_pre(const int* __restrict__ dst, const float* __restrict__ ea,
                      const float* __restrict__ x, const float* __restrict__ W1,
                      const float* __restrict__ W2, int* __restrict__ deg,
                      float* __restrict__ msum, unsigned short* __restrict__ xb,
                      unsigned short* __restrict__ w1t, unsigned short* __restrict__ w2t) {
  const int b = blockIdx.x;
  const int t = threadIdx.x;
  if (b < NBDEG) {
    int e = b * 256 + t;
    if (e < EE) atomicAdd(&deg[dst[e]], 1);
  } else if (b < NBDEG + NBMEAN) {
    float s[6] = {0, 0, 0, 0, 0, 0};
    for (int e = (b - NBDEG) * 256 + t; e < EE; e += NBMEAN * 256) {
#pragma unroll
      for (int d = 0; d < 6; d++) s[d] += ea[(size_t)e * 6 + d];
    }
    __shared__ float ls[6];
    if (t < 6) ls[t] = 0.f;
    __syncthreads();
#pragma unroll
    for (int d = 0; d < 6; d++) atomicAdd(&ls[d], s[d]);
    __syncthreads();
    if (t < 6) atomicAdd(&msum[t], ls[t]);
  } else if (b < NBDEG + NBMEAN + NBX) {
    int i = (b - NBDEG - NBMEAN) * 256 + t;  // i indexes 8-element chunks
    if (i < NN * 4) {
      int n = i >> 2, seg = i & 3;
      unsigned short v[8];
#pragma unroll
      for (int j = 0; j < 8; j++) {
        int k = seg * 8 + j;
        v[j] = (k < 29) ? f2bf(x[(size_t)n * 29 + k]) : (unsigned short)0;
      }
      *(short8*)(xb + (size_t)n * 32 + seg * 8) = *(short8*)v;
    }
  } else if (b < NBDEG + NBMEAN + NBX + NW1) {
    int i = (b - NBDEG - NBMEAN - NBX) * 256 + t;  // 8192 elems
    int row = i >> 5, k = i & 31;
    unsigned short v = (k < 29) ? f2bf(W1[(size_t)k * 256 + row]) : (unsigned short)0;
    w1t[((row >> 4) * 4 + (k >> 3)) * 128 + (row & 15) * 8 + (k & 7)] = v;
  } else {
    int i = (b - NBDEG - NBMEAN - NBX - NW1) * 256 + t;  // 65536 elems
    int row = i >> 8, k = i & 255;
    w2t[((row >> 4) * 32 + (k >> 3)) * 128 + (row & 15) * 8 + (k & 7)] = f2bf(W2[(size_t)k * 256 + row]);
  }
}

static constexpr int NBS = (NN + 255) / 256;  // 196 scan blocks

// block-level exclusive scan of deg -> rowptr (partial), block totals -> bsums.
// +2 trailing blocks compute per-layer edge params p1/p2.
__global__ void k_scan1(const int* __restrict__ deg, int* __restrict__ rowptr,
                        int* __restrict__ bsums, const float* __restrict__ We1,
                        const float* __restrict__ ae1, const float* __restrict__ We2,
                        const float* __restrict__ ae2, const float* __restrict__ msum,
                        float* __restrict__ p1, float* __restrict__ p2) {
  const int t = threadIdx.x;
  if (blockIdx.x >= NBS) {
    const int layer = blockIdx.x - NBS;
    const float* We = layer ? We2 : We1;
    const float* ae = layer ? ae2 : ae1;
    float* params = layer ? p2 : p1;
    __shared__ float vsh[24];
    if (t < 24) {
      int d = t >> 2, h = t & 3;
      float s = 0.f;
      for (int c = 0; c < 64; c++) s += We[d * 256 + h * 64 + c] * ae[h * 64 + c];
      vsh[t] = s;
      params[t] = s;
    }
    __syncthreads();
    if (t < 4) {
      float s = 0.f;
      const float invE = 1.0f / (float)EE;
#pragma unroll
      for (int d = 0; d < 6; d++) s += (msum[d] * invE) * vsh[d * 4 + t];
      params[24 + t] = s;
    }
    return;
  }
  __shared__ int sh[256];
  int i = blockIdx.x * 256 + t;
  int v = (i < NN) ? deg[i] : 0;
  sh[t] = v;
  __syncthreads();
  for (int off = 1; off < 256; off <<= 1) {
    int tv = (t >= off) ? sh[t - off] : 0;
    __syncthreads();
    sh[t] += tv;
    __syncthreads();
  }
  if (i < NN) rowptr[i] = sh[t] - v;  // exclusive within block
  if (t == 255) bsums[blockIdx.x] = sh[255];
}

// fused scan2+scan3: every block redundantly scans the 196 block sums,
// then applies its own block's exclusive prefix to rowptr.
__global__ void k_scan23(int* __restrict__ rowptr, const int* __restrict__ bsums, int nb) {
  __shared__ int sh[256];
  const int t = threadIdx.x;
  sh[t] = (t < nb) ? bsums[t] : 0;
  __syncthreads();
  for (int off = 1; off < 256; off <<= 1) {
    int tv = (t >= off) ? sh[t - off] : 0;
    __syncthreads();
    sh[t] += tv;  // inclusive scan
    __syncthreads();
  }
  const int add = (blockIdx.x == 0) ? 0 : sh[blockIdx.x - 1];
  int i = blockIdx.x * 256 + t;
  if (i < NN) rowptr[i] += add;
  if (i == 0) rowptr[NN] = EE;
}

// ---------------------------------------------------------------------------
// GEMM body (device fn): Y[M,256](bf16) = A[M,KP](bf16 row-major) @ B(tiled)
// + fused per-head logits. BM=64; 4 waves; wave w owns cols [64w,64w+64) = head w.
//
// R12: A tile staged in LDS, XOR-swizzled (one coalesced 4/32KB block read ->
// swizzled ds_write_b128; conflict-free ds_read_b128 frags).
//   swizzle f(o) = o ^ ((row(o)&7)<<4), row(o)=o/(2KP), same map write & read.
// R13: B register prefetch distance 2 (3 rolling buffers) + A frag LDS->reg
// prefetch distance 1.
template <int KP>
__device__ __forceinline__ void gemm_body(
    int bx, const unsigned short* __restrict__ A, const unsigned short* __restrict__ Bt,
    const float* __restrict__ a_s, const float* __restrict__ a_d,
    unsigned short* __restrict__ Y, float* __restrict__ als, float* __restrict__ ald, int M) {
  __shared__ __align__(16) unsigned short Ash[64 * KP];
  const int tid = threadIdx.x;
  const int lane = tid & 63;
  const int w = tid >> 6;
  const int l15 = lane & 15;
  const int quad = lane >> 4;
  const int row0 = bx * 64;

  // ---- stage A tile: coalesced global read (may read a few KB past the end
  // of A for the last block — lands in adjacent workspace buffers, harmless;
  // all outputs are row<M guarded) -> swizzled LDS write ----
  constexpr int STEPS = (64 * KP * 2) / (256 * 16);  // 1 (KP=32) or 8 (KP=256)
  {
    const char* Ab = (const char*)(A + (size_t)row0 * KP);
    uint4 stg[STEPS];
#pragma unroll
    for (int s = 0; s < STEPS; s++) stg[s] = *(const uint4*)(Ab + s * 4096 + tid * 16);
#pragma unroll
    for (int s = 0; s < STEPS; s++) {
      int o = s * 4096 + tid * 16;
      int row = o / (KP * 2);
      *(uint4*)((char*)Ash + (o ^ ((row & 7) << 4))) = stg[s];
    }
  }

  floatx4 acc[4][4];
#pragma unroll
  for (int i = 0; i < 4; i++)
#pragma unroll
    for (int j = 0; j < 4; j++) acc[i][j] = {0.f, 0.f, 0.f, 0.f};

  const unsigned short* pb[4];
#pragma unroll
  for (int j = 0; j < 4; j++)
    pb[j] = Bt + (size_t)((w * 4 + j) * (KP / 8) + quad) * 128 + l15 * 8;

  constexpr int NPH = KP / 32;
  short8 bfr[3][4];
#pragma unroll
  for (int j = 0; j < 4; j++) bfr[0][j] = *(const short8*)pb[j];  // overlaps staging
  if (NPH > 1) {
#pragma unroll
    for (int j = 0; j < 4; j++) {
      pb[j] += 512;  // 4 kc * 128
      bfr[1][j] = *(const short8*)pb[j];
    }
  }

  __syncthreads();

  // A fragment loader: conflict-free swizzled ds_read_b128 (row&7 == l15&7)
  auto ldA = [&](int ph, short8 (&dst)[4]) {
#pragma unroll
    for (int i = 0; i < 4; i++) {
      int lin = (i * 16 + l15) * (KP * 2) + ph * 64 + quad * 16;
      dst[i] = *(const short8*)((const char*)Ash + (lin ^ ((l15 & 7) << 4)));
    }
  };
  short8 af[2][4];
  ldA(0, af[0]);

#pragma unroll
  for (int ph = 0; ph < NPH; ph++) {
    if (ph + 2 < NPH) {  // B prefetch two phases ahead
#pragma unroll
      for (int j = 0; j < 4; j++) {
        pb[j] += 512;
        bfr[(ph + 2) % 3][j] = *(const short8*)pb[j];
      }
    }
    if (ph + 1 < NPH) ldA(ph + 1, af[(ph + 1) & 1]);  // A frag one ahead
#pragma unroll
    for (int i = 0; i < 4; i++)
#pragma unroll
      for (int j = 0; j < 4; j++)
        acc[i][j] = __builtin_amdgcn_mfma_f32_16x16x32_bf16(af[ph & 1][i], bfr[ph % 3][j], acc[i][j], 0, 0, 0);
  }
  // epilogue: C/D layout (m89) col = lane&15, row = (lane>>4)*4 + reg.
  float asc[4], adc[4];
#pragma unroll
  for (int j = 0; j < 4; j++) {
    asc[j] = a_s[w * 64 + j * 16 + l15];
    adc[j] = a_d[w * 64 + j * 16 + l15];
  }
#pragma unroll
  for (int i = 0; i < 4; i++) {
#pragma unroll
    for (int r = 0; r < 4; r++) {
      const int row = row0 + i * 16 + quad * 4 + r;
      unsigned ub[4];
      float hv[4];
#pragma unroll
      for (int j = 0; j < 4; j++) {
        ub[j] = f2bf(acc[i][j][r]);
        hv[j] = __uint_as_float(ub[j] << 16);  // dot uses rounded value (matches agg reads)
      }
      if (row < M) {
#pragma unroll
        for (int j = 0; j < 4; j++) Y[(size_t)row * 256 + w * 64 + j * 16 + l15] = (unsigned short)ub[j];
      }
      float ps = hv[0] * asc[0] + hv[1] * asc[1] + hv[2] * asc[2] + hv[3] * asc[3];
      float pd = hv[0] * adc[0] + hv[1] * adc[1] + hv[2] * adc[2] + hv[3] * adc[3];
#pragma unroll
      for (int off = 1; off < 16; off <<= 1) {
        ps += __shfl_xor(ps, off, 64);
        pd += __shfl_xor(pd, off, 64);
      }
      if (l15 == 0 && row < M) {
        als[row * 4 + w] = ps;
        ald[row * 4 + w] = pd;
      }
    }
  }
}

static constexpr int GB = (NN + 63) / 64;  // 782 GEMM blocks

// slot-ordered edc helper: gather ea row by edge id, project onto per-layer
// edge params, write SEQUENTIALLY in slot order (full lines).
__device__ __forceinline__ void edc_body(int slot, const int2* __restrict__ cse,
                                         const float* __restrict__ ea,
                                         const float* __restrict__ p, float* __restrict__ ed) {
  int e = cse[slot].y;
  const float* ep = ea + (size_t)e * 6;
  float2 e0 = *(const float2*)ep;
  float2 e1 = *(const float2*)(ep + 2);
  float2 e2 = *(const float2*)(ep + 4);
  float c[4];
#pragma unroll
  for (int h = 0; h < 4; h++) {
    c[h] = e0.x * p[0 * 4 + h] + e0.y * p[1 * 4 + h] + e1.x * p[2 * 4 + h] +
           e1.y * p[3 * 4 + h] + e2.x * p[4 * 4 + h] + e2.y * p[5 * 4 + h];
  }
  *(float4*)(ed + (size_t)slot * 4) = make_float4(c[0], c[1], c[2], c[3]);
}

// Fused: CSR scatter (1563 blks) ∥ layer-1 GEMM (782 blks).
// R14: scatter writes ONE 8B record {src, edge_id} per slot (R13's scattered
// float4 logit writes were 80MB of partial-line HBM evictions at 1.9TB/s).
__global__ __launch_bounds__(256, 2) void k_scatgemm1(
    const int* __restrict__ ei, const int* __restrict__ rowptr, int* __restrict__ cursor,
    int2* __restrict__ cse,
    const unsigned short* __restrict__ xb, const unsigned short* __restrict__ w1t,
    const float* __restrict__ as1, const float* __restrict__ ad1,
    unsigned short* __restrict__ hb, float* __restrict__ als, float* __restrict__ ald) {
  const int b = blockIdx.x;
  const int t = threadIdx.x;
  if (b < NBDEG) {
    int e = b * 256 + t;
    if (e >= EE) return;
    int s = ei[e];
    int d = ei[EE + e];
    int p = atomicAdd(&cursor[d], 1);
    int slot = rowptr[d] + p;
    cse[slot] = make_int2(s, e);
  } else {
    gemm_body<32>(b - NBDEG, xb, w1t, as1, ad1, hb, als, ald, NN);
  }
}

// R16: layer-1 edc only (the ed2 half rides in k_gemm2's grid where it
// overlaps latency-bound GEMM blocks for free).
__global__ void k_edc(const int2* __restrict__ cse, const float* __restrict__ ea,
                      const float* __restrict__ p1, float* __restrict__ ed1) {
  int slot = blockIdx.x * 256 + threadIdx.x;
  if (slot < EE) edc_body(slot, cse, ea, p1, ed1);
}

// layer-2 GEMM ∥ layer-2 edc (extra NBDEG partition blocks — R16).
__global__ __launch_bounds__(256, 2) void k_gemm2(
    const unsigned short* __restrict__ A, const unsigned short* __restrict__ Bt,
    const float* __restrict__ a_s, const float* __restrict__ a_d,
    unsigned short* __restrict__ Y, float* __restrict__ als, float* __restrict__ ald,
    const int2* __restrict__ cse, const float* __restrict__ ea,
    const float* __restrict__ p2, float* __restrict__ ed2) {
  if (blockIdx.x < GB) {
    gemm_body<256>(blockIdx.x, A, Bt, a_s, a_d, Y, als, ald, NN);
  } else {
    int slot = (blockIdx.x - GB) * 256 + threadIdx.x;
    if (slot < EE) edc_body(slot, cse, ea, p2, ed2);
  }
}

__device__ __forceinline__ float leaky02(float x) { return x > 0.f ? x : 0.2f * x; }

// GAT aggregation on bf16 h, one wave per node (per-node blocks — R17 revert:
// the R16 persistent grid-stride walk cost ~15% effective BW; same FETCH
// (119MB) at 3.0 vs 3.4 TB/s because each resident wave streamed 8 separated
// regions of rowptr/cse/edc instead of block-ordered contiguous ranges).
// Halves of the wave own even/odd CSR slots; chunked 4-deep gather (4
// independent 512B row gathers in flight per half-wave; chunk-tail guards are
// half-wave-uniform -> exec-masked, no divergence). edc read as slot-ordered
// stream. Logits are O(1) (0.1-scaled weights) so no max-subtraction.
// out = (Σ ex·h[src] + ex_self·h[n]) / Σ ex, +b, relu -> bf16.
__global__ __launch_bounds__(256) void k_agg(
    const unsigned short* __restrict__ hinb, const float* __restrict__ als,
    const float* __restrict__ ald, const int* __restrict__ rowptr, const int2* __restrict__ cse,
    const float* __restrict__ edc, const float* __restrict__ params, const float* __restrict__ bias,
    unsigned short* __restrict__ houtb) {
  const int lane = threadIdx.x & 63;
  const int n = blockIdx.x * 4 + (threadIdx.x >> 6);
  if (n >= NN) return;
  const int half = lane >> 5;  // 0: even slots, 1: odd slots
  const int sl = lane & 31;    // 16B chunk (8 channels) within row
  const int head = sl >> 3;

  const float aldn = ald[n * 4 + head];
  float acc[8];
  float ssum;
  {
    float slg = leaky02(als[n * 4 + head] + aldn + params[24 + head]);
    float exs = __expf(slg);
    float wgt = (half == 0) ? exs : 0.f;  // self term counted once (cross-half merge later)
    ssum = wgt;
    uint4 uv = *(const uint4*)(hinb + (size_t)n * 256 + sl * 8);
    acc[0] = bflo(uv.x) * wgt;
    acc[1] = bfhi(uv.x) * wgt;
    acc[2] = bflo(uv.y) * wgt;
    acc[3] = bfhi(uv.y) * wgt;
    acc[4] = bflo(uv.z) * wgt;
    acc[5] = bfhi(uv.z) * wgt;
    acc[6] = bflo(uv.w) * wgt;
    acc[7] = bfhi(uv.w) * wgt;
  }
  const int end = rowptr[n + 1];
  int s = rowptr[n] + half;
  while (s < end) {
    int sid[4];
    float edv[4];
    // meta for 4 slots (sequential within the node's CSR range — L1/L2 hits)
#pragma unroll
    for (int k = 0; k < 4; k++) {
      const int q = s + 2 * k;
      const bool v = q < end;           // uniform across the 32-lane half
      const int idx = v ? q : end - 1;  // clamped: valid address
      sid[k] = cse[idx].x;
      edv[k] = v ? edc[(size_t)idx * 4 + head] : 0.f;
    }
    // src-logit + h-row gathers, all in flight together
    float alv[4];
#pragma unroll
    for (int k = 0; k < 4; k++) alv[k] = als[(size_t)sid[k] * 4 + head];
    uint4 r[4];
#pragma unroll
    for (int k = 0; k < 4; k++) {
      r[k] = make_uint4(0u, 0u, 0u, 0u);
      if (s + 2 * k < end) r[k] = *(const uint4*)(hinb + (size_t)sid[k] * 256 + sl * 8);
    }
#pragma unroll
    for (int k = 0; k < 4; k++) {
      const float ex = (s + 2 * k < end) ? __expf(leaky02(alv[k] + aldn + edv[k])) : 0.f;
      acc[0] += bflo(r[k].x) * ex;
      acc[1] += bfhi(r[k].x) * ex;
      acc[2] += bflo(r[k].y) * ex;
      acc[3] += bfhi(r[k].y) * ex;
      acc[4] += bflo(r[k].z) * ex;
      acc[5] += bfhi(r[k].z) * ex;
      acc[6] += bflo(r[k].w) * ex;
      acc[7] += bfhi(r[k].w) * ex;
      ssum += ex;
    }
    s += 8;  // 4 slots per half per chunk
  }
  // merge even/odd halves (same channel set lives at lane and lane^32)
#pragma unroll
  for (int j = 0; j < 8; j++) acc[j] += __shfl_xor(acc[j], 32, 64);
  ssum += __shfl_xor(ssum, 32, 64);
  if (half == 0) {
    const float inv = 1.f / (ssum + 1e-16f);
    float4 b0 = *(const float4*)(bias + sl * 8);
    float4 b1 = *(const float4*)(bias + sl * 8 + 4);
    const float bb[8] = {b0.x, b0.y, b0.z, b0.w, b1.x, b1.y, b1.z, b1.w};
    uint p[4];
#pragma unroll
    for (int j = 0; j < 4; j++) {
      float e0 = fmaxf(acc[2 * j] * inv + bb[2 * j], 0.f);
      float e1 = fmaxf(acc[2 * j + 1] * inv + bb[2 * j + 1], 0.f);
      p[j] = (uint)f2bf(e0) | ((uint)f2bf(e1) << 16);
    }
    *(uint4*)(houtb + (size_t)n * 256 + sl * 8) = make_uint4(p[0], p[1], p[2], p[3]);
  }
}

// per-graph mean pool (bf16 in) + readout linear (256->12).
// Node range split across both 128-lane halves (R10 idled threads 128-255).
__global__ __launch_bounds__(256) void k_pool(const unsigned short* __restrict__ hb,
                                              const int* __restrict__ batch,
                                              const float* __restrict__ Wl,
                                              const float* __restrict__ bl,
                                              float* __restrict__ out) {
  int g = blockIdx.x;
  int t = threadIdx.x;
  int lo = 0, hi = NN;
  while (lo < hi) {
    int mid = (lo + hi) >> 1;
    if (batch[mid] < g) lo = mid + 1; else hi = mid;
  }
  int start = lo;
  hi = NN;
  while (lo < hi) {
    int mid = (lo + hi) >> 1;
    if (batch[mid] < g + 1) lo = mid + 1; else hi = mid;
  }
  int end = lo;
  const int mid2 = start + ((end - start) >> 1);
  __shared__ float sp[256], sq[256];
  {
    const int c = t & 127;
    const int hseg = t >> 7;  // 0: [start,mid2), 1: [mid2,end)
    const int a = hseg ? mid2 : start;
    const int b = hseg ? end : mid2;
    float s0 = 0.f, s1 = 0.f;
    for (int n2 = a; n2 < b; n2++) {
      uint u = ((const uint*)(hb + (size_t)n2 * 256))[c];
      s0 += bflo(u);
      s1 += bfhi(u);
    }
    float* dst = hseg ? sq : sp;
    dst[2 * c] = s0;
    dst[2 * c + 1] = s1;
  }
  __syncthreads();
  if (t < TASKS) {
    float invc = 1.f / fmaxf((float)(end - start), 1.f);
    float o = bl[t];
    for (int c = 0; c < 256; c++) o += (sp[c] + sq[c]) * invc * Wl[c * 12 + t];
    out[(size_t)g * 12 + t] = o;
  }
}

// ---------------------------------------------------------------------------
extern "C" void kernel_launch(void* const* d_in, const int* in_sizes, int n_in,
                              void* d_out, int out_size, void* d_ws, size_t ws_size,
                              hipStream_t stream) {
  const float* x = (const float*)d_in[0];
  const int* ei = (const int*)d_in[1];
  const float* ea = (const float*)d_in[2];
  const int* batch = (const int*)d_in[3];
  const float* W1 = (const float*)d_in[4];
  const float* as1 = (const float*)d_in[5];
  const float* ad1 = (const float*)d_in[6];
  const float* We1 = (const float*)d_in[7];
  const float* ae1 = (const float*)d_in[8];
  const float* b1 = (const float*)d_in[9];
  const float* W2 = (const float*)d_in[10];
  const float* as2 = (const float*)d_in[11];
  const float* ad2 = (const float*)d_in[12];
  const float* We2 = (const float*)d_in[13];
  const float* ae2 = (const float*)d_in[14];
  const float* b2 = (const float*)d_in[15];
  const float* Wl = (const float*)d_in[16];
  const float* bl = (const float*)d_in[17];
  float* out = (float*)d_out;

  // workspace carve-up (256B aligned)
  char* ws = (char*)d_ws;
  size_t off = 0;
  auto take = [&](size_t bytes) -> char* {
    char* p = ws + off;
    off = (off + bytes + 255) & ~(size_t)255;
    return p;
  };
  float* msum = (float*)take(8 * 4);
  int* deg = (int*)take((size_t)NN * 4);
  int* cursor = (int*)take((size_t)NN * 4);
  size_t zero_end = off;  // msum+deg+cursor need zeroing
  int* rowptr = (int*)take((size_t)(NN + 1) * 4);
  int* bsums = (int*)take(256 * 4);
  int2* cse = (int2*)take((size_t)EE * 8);
  float* ed1 = (float*)take((size_t)EE * 4 * 4);
  float* ed2 = (float*)take((size_t)EE * 4 * 4);
  float* p1 = (float*)take(32 * 4);
  float* p2 = (float*)take(32 * 4);
  float* als = (float*)take((size_t)NN * 4 * 4);
  float* ald = (float*)take((size_t)NN * 4 * 4);
  unsigned short* hb = (unsigned short*)take((size_t)NN * 256 * 2);  // GEMM out (bf16)
  unsigned short* ab = (unsigned short*)take((size_t)NN * 256 * 2);  // agg out (bf16)
  unsigned short* xb = (unsigned short*)take((size_t)NN * 32 * 2);
  unsigned short* w1t = (unsigned short*)take((size_t)256 * 32 * 2);
  unsigned short* w2t = (unsigned short*)take((size_t)256 * 256 * 2);
  (void)ws_size;

  hipMemsetAsync(ws, 0, zero_end, stream);

  k_pre<<<NBDEG + NBMEAN + NBX + NW1 + NW2, 256, 0, stream>>>(ei + EE, ea, x, W1, W2,
                                                              deg, msum, xb, w1t, w2t);
  k_scan1<<<NBS + 2, 256, 0, stream>>>(deg, rowptr, bsums, We1, ae1, We2, ae2, msum, p1, p2);
  k_scan23<<<NBS, 256, 0, stream>>>(rowptr, bsums, NBS);

  // CSR scatter ∥ layer-1 GEMM (independent partitions)
  k_scatgemm1<<<NBDEG + GB, 256, 0, stream>>>(ei, rowptr, cursor, cse,
                                              xb, w1t, as1, ad1, hb, als, ald);

  // slot-ordered edc for layer 1 (stream writes; ea gathered once)
  k_edc<<<NBDEG, 256, 0, stream>>>(cse, ea, p1, ed1);

  // Layer 1 (cont.)
  k_agg<<<NN / 4, 256, 0, stream>>>(hb, als, ald, rowptr, cse, ed1, p1, b1, ab);

  // Layer 2 (GEMM ∥ ed2 partition)
  k_gemm2<<<GB + NBDEG, 256, 0, stream>>>(ab, w2t, as2, ad2, hb, als, ald,
                                          cse, ea, p2, ed2);
  k_agg<<<NN / 4, 256, 0, stream>>>(hb, als, ald, rowptr, cse, ed2, p2, b2, ab);

  // Pool + readout
  k_pool<<<GG, 256, 0, stream>>>(ab, batch, Wl, bl, out);
}

// Round 9
// 286.172 us; speedup vs baseline: 1.0798x; 1.0324x over previous
//
#include <hip/hip_runtime.h>
#include <math.h>

// Problem constants (fixed by reference)
static constexpr int NN = 50000;   // nodes
static constexpr int EE = 400000;  // edges (without self loops)
static constexpr int GG = 2048;    // graphs
static constexpr int TASKS = 12;

typedef __attribute__((ext_vector_type(8))) short short8;   // 8 bf16 (4 VGPRs)
typedef __attribute__((ext_vector_type(4))) float floatx4;  // MFMA acc

__device__ __forceinline__ unsigned short f2bf(float f) {
  unsigned u = __float_as_uint(f);
  u = u + 0x7fffu + ((u >> 16) & 1u);  // RNE
  return (unsigned short)(u >> 16);
}
__device__ __forceinline__ float bflo(unsigned u) { return __uint_as_float(u << 16); }
__device__ __forceinline__ float bfhi(unsigned u) { return __uint_as_float(u & 0xffff0000u); }

// ---------------------------------------------------------------------------
// Fused independent preamble, grid-partitioned:
//   [0,NBDEG)       in-degree histogram (distributed atomics — safe)
//   [+NBMEAN)       edge_attr mean sums (LDS pre-reduce, 6 atomics/blk — R5 lesson)
//   [+NBX)          x -> bf16 [NN][32] zero-padded (8 outputs/thread)
//   [+NW1)          W1 -> bf16 fragment-tiled [row>>4][kc][row&15][8], K=32
//   [+NW2)          W2 -> bf16 fragment-tiled [row>>4][kc][row&15][8], K=256
// Tiled layout makes each GEMM B-fragment load a contiguous 1KB wave burst
// (R9's B^T row-major gave 16 scattered 64B requests per load instr).
static constexpr int NBDEG = (EE + 255) / 256;     // 1563
static constexpr int NBMEAN = 256;
static constexpr int NBX = (NN * 4 + 255) / 256;   // 782 (thread = 8 bf16 outs)
static constexpr int NW1 = 32;
static constexpr int NW2 = 256;
__global__ void k_pre(const int* __restrict__ dst, const float* __restrict__ ea,
                      const float* __restrict__ x, const float* __restrict__ W1,
                      const float* __restrict__ W2, int* __restrict__ deg,
                      float* __restrict__ msum, unsigned short* __restrict__ xb,
                      unsigned short* __restrict__ w1t, unsigned short* __restrict__ w2t) {
  const int b = blockIdx.x;
  const int t = threadIdx.x;
  if (b < NBDEG) {
    int e = b * 256 + t;
    if (e < EE) atomicAdd(&deg[dst[e]], 1);
  } else if (b < NBDEG + NBMEAN) {
    float s[6] = {0, 0, 0, 0, 0, 0};
    for (int e = (b - NBDEG) * 256 + t; e < EE; e += NBMEAN * 256) {
#pragma unroll
      for (int d = 0; d < 6; d++) s[d] += ea[(size_t)e * 6 + d];
    }
    __shared__ float ls[6];
    if (t < 6) ls[t] = 0.f;
    __syncthreads();
#pragma unroll
    for (int d = 0; d < 6; d++) atomicAdd(&ls[d], s[d]);
    __syncthreads();
    if (t < 6) atomicAdd(&msum[t], ls[t]);
  } else if (b < NBDEG + NBMEAN + NBX) {
    int i = (b - NBDEG - NBMEAN) * 256 + t;  // i indexes 8-element chunks
    if (i < NN * 4) {
      int n = i >> 2, seg = i & 3;
      unsigned short v[8];
#pragma unroll
      for (int j = 0; j < 8; j++) {
        int k = seg * 8 + j;
        v[j] = (k < 29) ? f2bf(x[(size_t)n * 29 + k]) : (unsigned short)0;
      }
      *(short8*)(xb + (size_t)n * 32 + seg * 8) = *(short8*)v;
    }
  } else if (b < NBDEG + NBMEAN + NBX + NW1) {
    int i = (b - NBDEG - NBMEAN - NBX) * 256 + t;  // 8192 elems
    int row = i >> 5, k = i & 31;
    unsigned short v = (k < 29) ? f2bf(W1[(size_t)k * 256 + row]) : (unsigned short)0;
    w1t[((row >> 4) * 4 + (k >> 3)) * 128 + (row & 15) * 8 + (k & 7)] = v;
  } else {
    int i = (b - NBDEG - NBMEAN - NBX - NW1) * 256 + t;  // 65536 elems
    int row = i >> 8, k = i & 255;
    w2t[((row >> 4) * 32 + (k >> 3)) * 128 + (row & 15) * 8 + (k & 7)] = f2bf(W2[(size_t)k * 256 + row]);
  }
}

static constexpr int NBS = (NN + 255) / 256;  // 196 scan blocks

// block-level exclusive scan of deg -> rowptr (partial), block totals -> bsums.
// +2 trailing blocks compute per-layer edge params p1/p2 (consumed by the
// scatter partition of k_scatgemm1 and by k_agg's self-loop term).
__global__ void k_scan1(const int* __restrict__ deg, int* __restrict__ rowptr,
                        int* __restrict__ bsums, const float* __restrict__ We1,
                        const float* __restrict__ ae1, const float* __restrict__ We2,
                        const float* __restrict__ ae2, const float* __restrict__ msum,
                        float* __restrict__ p1, float* __restrict__ p2) {
  const int t = threadIdx.x;
  if (blockIdx.x >= NBS) {
    const int layer = blockIdx.x - NBS;
    const float* We = layer ? We2 : We1;
    const float* ae = layer ? ae2 : ae1;
    float* params = layer ? p2 : p1;
    __shared__ float vsh[24];
    if (t < 24) {
      int d = t >> 2, h = t & 3;
      float s = 0.f;
      for (int c = 0; c < 64; c++) s += We[d * 256 + h * 64 + c] * ae[h * 64 + c];
      vsh[t] = s;
      params[t] = s;
    }
    __syncthreads();
    if (t < 4) {
      float s = 0.f;
      const float invE = 1.0f / (float)EE;
#pragma unroll
      for (int d = 0; d < 6; d++) s += (msum[d] * invE) * vsh[d * 4 + t];
      params[24 + t] = s;
    }
    return;
  }
  __shared__ int sh[256];
  int i = blockIdx.x * 256 + t;
  int v = (i < NN) ? deg[i] : 0;
  sh[t] = v;
  __syncthreads();
  for (int off = 1; off < 256; off <<= 1) {
    int tv = (t >= off) ? sh[t - off] : 0;
    __syncthreads();
    sh[t] += tv;
    __syncthreads();
  }
  if (i < NN) rowptr[i] = sh[t] - v;  // exclusive within block
  if (t == 255) bsums[blockIdx.x] = sh[255];
}

// fused scan2+scan3: every block redundantly scans the 196 block sums,
// then applies its own block's exclusive prefix to rowptr.
__global__ void k_scan23(int* __restrict__ rowptr, const int* __restrict__ bsums, int nb) {
  __shared__ int sh[256];
  const int t = threadIdx.x;
  sh[t] = (t < nb) ? bsums[t] : 0;
  __syncthreads();
  for (int off = 1; off < 256; off <<= 1) {
    int tv = (t >= off) ? sh[t - off] : 0;
    __syncthreads();
    sh[t] += tv;  // inclusive scan
    __syncthreads();
  }
  const int add = (blockIdx.x == 0) ? 0 : sh[blockIdx.x - 1];
  int i = blockIdx.x * 256 + t;
  if (i < NN) rowptr[i] += add;
  if (i == 0) rowptr[NN] = EE;
}

// ---------------------------------------------------------------------------
// GEMM body (device fn): Y[M,256](bf16) = A[M,KP](bf16 row-major) @ B(tiled)
// + fused per-head logits. BM=64; 4 waves; wave w owns cols [64w,64w+64) = head w.
//
// R12: A tile staged in LDS, XOR-swizzled (one coalesced 4/32KB block read ->
// swizzled ds_write_b128; conflict-free ds_read_b128 frags).
//   swizzle f(o) = o ^ ((row(o)&7)<<4), row(o)=o/(2KP), same map write & read.
// R13: B register prefetch distance 2 (3 rolling buffers) + A frag LDS->reg
// prefetch distance 1.
// R19: staging reads clamped to A's valid range (last block previously
// over-read a few KB past A; clamped rows only feed discarded row>=M outputs).
template <int KP>
__device__ __forceinline__ void gemm_body(
    int bx, const unsigned short* __restrict__ A, const unsigned short* __restrict__ Bt,
    const float* __restrict__ a_s, const float* __restrict__ a_d,
    unsigned short* __restrict__ Y, float* __restrict__ als, float* __restrict__ ald, int M) {
  __shared__ __align__(16) unsigned short Ash[64 * KP];
  const int tid = threadIdx.x;
  const int lane = tid & 63;
  const int w = tid >> 6;
  const int l15 = lane & 15;
  const int quad = lane >> 4;
  const int row0 = bx * 64;

  // ---- stage A tile: coalesced clamped global read -> swizzled LDS write ----
  constexpr int STEPS = (64 * KP * 2) / (256 * 16);  // 1 (KP=32) or 8 (KP=256)
  {
    const size_t limit = (size_t)M * (KP * 2) - 16;  // last valid 16B read
    uint4 stg[STEPS];
#pragma unroll
    for (int s = 0; s < STEPS; s++) {
      size_t og = (size_t)row0 * (KP * 2) + s * 4096 + tid * 16;
      if (og > limit) og = limit;  // clamp: affects only discarded rows >= M
      stg[s] = *(const uint4*)((const char*)A + og);
    }
#pragma unroll
    for (int s = 0; s < STEPS; s++) {
      int o = s * 4096 + tid * 16;
      int row = o / (KP * 2);
      *(uint4*)((char*)Ash + (o ^ ((row & 7) << 4))) = stg[s];
    }
  }

  floatx4 acc[4][4];
#pragma unroll
  for (int i = 0; i < 4; i++)
#pragma unroll
    for (int j = 0; j < 4; j++) acc[i][j] = {0.f, 0.f, 0.f, 0.f};

  const unsigned short* pb[4];
#pragma unroll
  for (int j = 0; j < 4; j++)
    pb[j] = Bt + (size_t)((w * 4 + j) * (KP / 8) + quad) * 128 + l15 * 8;

  constexpr int NPH = KP / 32;
  short8 bfr[3][4];
#pragma unroll
  for (int j = 0; j < 4; j++) bfr[0][j] = *(const short8*)pb[j];  // overlaps staging
  if (NPH > 1) {
#pragma unroll
    for (int j = 0; j < 4; j++) {
      pb[j] += 512;  // 4 kc * 128
      bfr[1][j] = *(const short8*)pb[j];
    }
  }

  __syncthreads();

  // A fragment loader: conflict-free swizzled ds_read_b128 (row&7 == l15&7)
  auto ldA = [&](int ph, short8 (&dst)[4]) {
#pragma unroll
    for (int i = 0; i < 4; i++) {
      int lin = (i * 16 + l15) * (KP * 2) + ph * 64 + quad * 16;
      dst[i] = *(const short8*)((const char*)Ash + (lin ^ ((l15 & 7) << 4)));
    }
  };
  short8 af[2][4];
  ldA(0, af[0]);

#pragma unroll
  for (int ph = 0; ph < NPH; ph++) {
    if (ph + 2 < NPH) {  // B prefetch two phases ahead
#pragma unroll
      for (int j = 0; j < 4; j++) {
        pb[j] += 512;
        bfr[(ph + 2) % 3][j] = *(const short8*)pb[j];
      }
    }
    if (ph + 1 < NPH) ldA(ph + 1, af[(ph + 1) & 1]);  // A frag one ahead
#pragma unroll
    for (int i = 0; i < 4; i++)
#pragma unroll
      for (int j = 0; j < 4; j++)
        acc[i][j] = __builtin_amdgcn_mfma_f32_16x16x32_bf16(af[ph & 1][i], bfr[ph % 3][j], acc[i][j], 0, 0, 0);
  }
  // epilogue: C/D layout (m89) col = lane&15, row = (lane>>4)*4 + reg.
  float asc[4], adc[4];
#pragma unroll
  for (int j = 0; j < 4; j++) {
    asc[j] = a_s[w * 64 + j * 16 + l15];
    adc[j] = a_d[w * 64 + j * 16 + l15];
  }
#pragma unroll
  for (int i = 0; i < 4; i++) {
#pragma unroll
    for (int r = 0; r < 4; r++) {
      const int row = row0 + i * 16 + quad * 4 + r;
      unsigned ub[4];
      float hv[4];
#pragma unroll
      for (int j = 0; j < 4; j++) {
        ub[j] = f2bf(acc[i][j][r]);
        hv[j] = __uint_as_float(ub[j] << 16);  // dot uses rounded value (matches agg reads)
      }
      if (row < M) {
#pragma unroll
        for (int j = 0; j < 4; j++) Y[(size_t)row * 256 + w * 64 + j * 16 + l15] = (unsigned short)ub[j];
      }
      float ps = hv[0] * asc[0] + hv[1] * asc[1] + hv[2] * asc[2] + hv[3] * asc[3];
      float pd = hv[0] * adc[0] + hv[1] * adc[1] + hv[2] * adc[2] + hv[3] * adc[3];
#pragma unroll
      for (int off = 1; off < 16; off <<= 1) {
        ps += __shfl_xor(ps, off, 64);
        pd += __shfl_xor(pd, off, 64);
      }
      if (l15 == 0 && row < M) {
        als[row * 4 + w] = ps;
        ald[row * 4 + w] = pd;
      }
    }
  }
}

static constexpr int GB = (NN + 63) / 64;  // 782 GEMM blocks

// Fused: CSR scatter (1563 blks) ∥ layer-1 GEMM (782 blks).
// R18/R19: scatter computes BOTH layers' per-edge logit contributions AT
// SCATTER TIME (overlapping GEMM1's latency stalls — R3's winning trick) and
// writes ONE 64B line-aligned record
//   {src(bitcast), eid(bitcast), 0, 0, ed1[4], ed2[4], 0,0,0,0}
// with four ADJACENT float4 stores: exactly one fully-dirtied line per edge.
// (R3's 3-stream form dirtied ~3 partial lines/edge -> 80MB scattered writes
// at 1.9TB/s.) All stores are float4 (src/eid bit-cast) — uniform type.
__global__ __launch_bounds__(256, 2) void k_scatgemm1(
    const int* __restrict__ ei, const int* __restrict__ rowptr, int* __restrict__ cursor,
    float* __restrict__ rec, const float* __restrict__ ea,
    const float* __restrict__ p1, const float* __restrict__ p2,
    const unsigned short* __restrict__ xb, const unsigned short* __restrict__ w1t,
    const float* __restrict__ as1, const float* __restrict__ ad1,
    unsigned short* __restrict__ hb, float* __restrict__ als, float* __restrict__ ald) {
  const int b = blockIdx.x;
  const int t = threadIdx.x;
  if (b < NBDEG) {
    int e = b * 256 + t;
    if (e >= EE) return;
    int s = ei[e];
    int d = ei[EE + e];
    int p = atomicAdd(&cursor[d], 1);
    int slot = rowptr[d] + p;
    // per-edge logit contributions, both layers (identical FMA order to R3/R5)
    const float* ep = ea + (size_t)e * 6;
    float2 e0 = *(const float2*)ep;
    float2 e1 = *(const float2*)(ep + 2);
    float2 e2 = *(const float2*)(ep + 4);
    float c1[4], c2[4];
#pragma unroll
    for (int h = 0; h < 4; h++) {
      c1[h] = e0.x * p1[0 * 4 + h] + e0.y * p1[1 * 4 + h] + e1.x * p1[2 * 4 + h] +
              e1.y * p1[3 * 4 + h] + e2.x * p1[4 * 4 + h] + e2.y * p1[5 * 4 + h];
      c2[h] = e0.x * p2[0 * 4 + h] + e0.y * p2[1 * 4 + h] + e1.x * p2[2 * 4 + h] +
              e1.y * p2[3 * 4 + h] + e2.x * p2[4 * 4 + h] + e2.y * p2[5 * 4 + h];
    }
    float* rp = rec + (size_t)slot * 16;  // 64B record, 64B-aligned
    *(float4*)rp = make_float4(__int_as_float(s), __int_as_float(e), 0.f, 0.f);
    *(float4*)(rp + 4) = make_float4(c1[0], c1[1], c1[2], c1[3]);
    *(float4*)(rp + 8) = make_float4(c2[0], c2[1], c2[2], c2[3]);
    *(float4*)(rp + 12) = make_float4(0.f, 0.f, 0.f, 0.f);  // full-line dirty
  } else {
    gemm_body<32>(b - NBDEG, xb, w1t, as1, ad1, hb, als, ald, NN);
  }
}

// layer-2 GEMM standalone (clean — R7 showed an edc rider here cost ~5µs:
// rider blocks inherit the kernel's 32KB static LDS and occupy full CU slots).
__global__ __launch_bounds__(256, 2) void k_gemm2(
    const unsigned short* __restrict__ A, const unsigned short* __restrict__ Bt,
    const float* __restrict__ a_s, const float* __restrict__ a_d,
    unsigned short* __restrict__ Y, float* __restrict__ als, float* __restrict__ ald) {
  gemm_body<256>(blockIdx.x, A, Bt, a_s, a_d, Y, als, ald, NN);
}

__device__ __forceinline__ float leaky02(float x) { return x > 0.f ? x : 0.2f * x; }

// GAT aggregation on bf16 h, one wave per node (per-node blocks — R17: block
// order must track address order; persistent striding cost 15% BW). Halves of
// the wave own even/odd CSR slots; chunked 4-deep gather (4 independent 512B
// row gathers in flight per half-wave; chunk-tail guards half-wave-uniform ->
// exec-masked). R18: meta = one 64B record/slot; src and this layer's
// edc[head] come from the SAME broadcast line (edoff selects layer: 4=ed1,
// 8=ed2). Logits O(1) -> no max-subtraction; exp can't overflow.
// out = (Σ ex·h[src] + ex_self·h[n]) / Σ ex, +b, relu -> bf16.
__global__ __launch_bounds__(256) void k_agg(
    const unsigned short* __restrict__ hinb, const float* __restrict__ als,
    const float* __restrict__ ald, const int* __restrict__ rowptr, const float* __restrict__ rec,
    int edoff, const float* __restrict__ params, const float* __restrict__ bias,
    unsigned short* __restrict__ houtb) {
  const int lane = threadIdx.x & 63;
  const int n = blockIdx.x * 4 + (threadIdx.x >> 6);
  if (n >= NN) return;
  const int half = lane >> 5;  // 0: even slots, 1: odd slots
  const int sl = lane & 31;    // 16B chunk (8 channels) within row
  const int head = sl >> 3;

  const float aldn = ald[n * 4 + head];
  float acc[8];
  float ssum;
  {
    float slg = leaky02(als[n * 4 + head] + aldn + params[24 + head]);
    float exs = __expf(slg);
    float wgt = (half == 0) ? exs : 0.f;  // self term counted once (cross-half merge later)
    ssum = wgt;
    uint4 uv = *(const uint4*)(hinb + (size_t)n * 256 + sl * 8);
    acc[0] = bflo(uv.x) * wgt;
    acc[1] = bfhi(uv.x) * wgt;
    acc[2] = bflo(uv.y) * wgt;
    acc[3] = bfhi(uv.y) * wgt;
    acc[4] = bflo(uv.z) * wgt;
    acc[5] = bfhi(uv.z) * wgt;
    acc[6] = bflo(uv.w) * wgt;
    acc[7] = bfhi(uv.w) * wgt;
  }
  const int end = rowptr[n + 1];
  int s = rowptr[n] + half;
  while (s < end) {
    int sid[4];
    float edv[4];
    // meta for 4 slots — one broadcast 64B line each (sequential in slot order)
#pragma unroll
    for (int k = 0; k < 4; k++) {
      const int q = s + 2 * k;
      const bool v = q < end;           // uniform across the 32-lane half
      const int idx = v ? q : end - 1;  // clamped: valid address
      const float* rp = rec + (size_t)idx * 16;
      sid[k] = __float_as_int(rp[0]);
      edv[k] = v ? rp[edoff + head] : 0.f;
    }
    // src-logit + h-row gathers, all in flight together
    float alv[4];
#pragma unroll
    for (int k = 0; k < 4; k++) alv[k] = als[(size_t)sid[k] * 4 + head];
    uint4 r[4];
#pragma unroll
    for (int k = 0; k < 4; k++) {
      r[k] = make_uint4(0u, 0u, 0u, 0u);
      if (s + 2 * k < end) r[k] = *(const uint4*)(hinb + (size_t)sid[k] * 256 + sl * 8);
    }
#pragma unroll
    for (int k = 0; k < 4; k++) {
      const float ex = (s + 2 * k < end) ? __expf(leaky02(alv[k] + aldn + edv[k])) : 0.f;
      acc[0] += bflo(r[k].x) * ex;
      acc[1] += bfhi(r[k].x) * ex;
      acc[2] += bflo(r[k].y) * ex;
      acc[3] += bfhi(r[k].y) * ex;
      acc[4] += bflo(r[k].z) * ex;
      acc[5] += bfhi(r[k].z) * ex;
      acc[6] += bflo(r[k].w) * ex;
      acc[7] += bfhi(r[k].w) * ex;
      ssum += ex;
    }
    s += 8;  // 4 slots per half per chunk
  }
  // merge even/odd halves (same channel set lives at lane and lane^32)
#pragma unroll
  for (int j = 0; j < 8; j++) acc[j] += __shfl_xor(acc[j], 32, 64);
  ssum += __shfl_xor(ssum, 32, 64);
  if (half == 0) {
    const float inv = 1.f / (ssum + 1e-16f);
    float4 b0 = *(const float4*)(bias + sl * 8);
    float4 b1 = *(const float4*)(bias + sl * 8 + 4);
    const float bb[8] = {b0.x, b0.y, b0.z, b0.w, b1.x, b1.y, b1.z, b1.w};
    uint p[4];
#pragma unroll
    for (int j = 0; j < 4; j++) {
      float e0 = fmaxf(acc[2 * j] * inv + bb[2 * j], 0.f);
      float e1 = fmaxf(acc[2 * j + 1] * inv + bb[2 * j + 1], 0.f);
      p[j] = (uint)f2bf(e0) | ((uint)f2bf(e1) << 16);
    }
    *(uint4*)(houtb + (size_t)n * 256 + sl * 8) = make_uint4(p[0], p[1], p[2], p[3]);
  }
}

// per-graph mean pool (bf16 in) + readout linear (256->12).
// Node range split across both 128-lane halves (R10 idled threads 128-255).
__global__ __launch_bounds__(256) void k_pool(const unsigned short* __restrict__ hb,
                                              const int* __restrict__ batch,
                                              const float* __restrict__ Wl,
                                              const float* __restrict__ bl,
                                              float* __restrict__ out) {
  int g = blockIdx.x;
  int t = threadIdx.x;
  int lo = 0, hi = NN;
  while (lo < hi) {
    int mid = (lo + hi) >> 1;
    if (batch[mid] < g) lo = mid + 1; else hi = mid;
  }
  int start = lo;
  hi = NN;
  while (lo < hi) {
    int mid = (lo + hi) >> 1;
    if (batch[mid] < g + 1) lo = mid + 1; else hi = mid;
  }
  int end = lo;
  const int mid2 = start + ((end - start) >> 1);
  __shared__ float sp[256], sq[256];
  {
    const int c = t & 127;
    const int hseg = t >> 7;  // 0: [start,mid2), 1: [mid2,end)
    const int a = hseg ? mid2 : start;
    const int b = hseg ? end : mid2;
    float s0 = 0.f, s1 = 0.f;
    for (int n2 = a; n2 < b; n2++) {
      uint u = ((const uint*)(hb + (size_t)n2 * 256))[c];
      s0 += bflo(u);
      s1 += bfhi(u);
    }
    float* dst = hseg ? sq : sp;
    dst[2 * c] = s0;
    dst[2 * c + 1] = s1;
  }
  __syncthreads();
  if (t < TASKS) {
    float invc = 1.f / fmaxf((float)(end - start), 1.f);
    float o = bl[t];
    for (int c = 0; c < 256; c++) o += (sp[c] + sq[c]) * invc * Wl[c * 12 + t];
    out[(size_t)g * 12 + t] = o;
  }
}

// ---------------------------------------------------------------------------
extern "C" void kernel_launch(void* const* d_in, const int* in_sizes, int n_in,
                              void* d_out, int out_size, void* d_ws, size_t ws_size,
                              hipStream_t stream) {
  const float* x = (const float*)d_in[0];
  const int* ei = (const int*)d_in[1];
  const float* ea = (const float*)d_in[2];
  const int* batch = (const int*)d_in[3];
  const float* W1 = (const float*)d_in[4];
  const float* as1 = (const float*)d_in[5];
  const float* ad1 = (const float*)d_in[6];
  const float* We1 = (const float*)d_in[7];
  const float* ae1 = (const float*)d_in[8];
  const float* b1 = (const float*)d_in[9];
  const float* W2 = (const float*)d_in[10];
  const float* as2 = (const float*)d_in[11];
  const float* ad2 = (const float*)d_in[12];
  const float* We2 = (const float*)d_in[13];
  const float* ae2 = (const float*)d_in[14];
  const float* b2 = (const float*)d_in[15];
  const float* Wl = (const float*)d_in[16];
  const float* bl = (const float*)d_in[17];
  float* out = (float*)d_out;

  // workspace carve-up (256B aligned)
  char* ws = (char*)d_ws;
  size_t off = 0;
  auto take = [&](size_t bytes) -> char* {
    char* p = ws + off;
    off = (off + bytes + 255) & ~(size_t)255;
    return p;
  };
  float* msum = (float*)take(8 * 4);
  int* deg = (int*)take((size_t)NN * 4);
  int* cursor = (int*)take((size_t)NN * 4);
  size_t zero_end = off;  // msum+deg+cursor need zeroing
  int* rowptr = (int*)take((size_t)(NN + 1) * 4);
  int* bsums = (int*)take(256 * 4);
  float* rec = (float*)take((size_t)EE * 64);  // 64B/edge combined record
  float* p1 = (float*)take(32 * 4);
  float* p2 = (float*)take(32 * 4);
  float* als = (float*)take((size_t)NN * 4 * 4);
  float* ald = (float*)take((size_t)NN * 4 * 4);
  unsigned short* hb = (unsigned short*)take((size_t)NN * 256 * 2);  // GEMM out (bf16)
  unsigned short* ab = (unsigned short*)take((size_t)NN * 256 * 2);  // agg out (bf16)
  unsigned short* xb = (unsigned short*)take((size_t)NN * 32 * 2);
  unsigned short* w1t = (unsigned short*)take((size_t)256 * 32 * 2);
  unsigned short* w2t = (unsigned short*)take((size_t)256 * 256 * 2);
  (void)ws_size;

  hipMemsetAsync(ws, 0, zero_end, stream);

  k_pre<<<NBDEG + NBMEAN + NBX + NW1 + NW2, 256, 0, stream>>>(ei + EE, ea, x, W1, W2,
                                                              deg, msum, xb, w1t, w2t);
  k_scan1<<<NBS + 2, 256, 0, stream>>>(deg, rowptr, bsums, We1, ae1, We2, ae2, msum, p1, p2);
  k_scan23<<<NBS, 256, 0, stream>>>(rowptr, bsums, NBS);

  // CSR scatter (with both layers' edc, one 64B line/edge) ∥ layer-1 GEMM
  k_scatgemm1<<<NBDEG + GB, 256, 0, stream>>>(ei, rowptr, cursor, rec, ea, p1, p2,
                                              xb, w1t, as1, ad1, hb, als, ald);

  // Layer 1 (cont.)
  k_agg<<<NN / 4, 256, 0, stream>>>(hb, als, ald, rowptr, rec, 4, p1, b1, ab);

  // Layer 2
  k_gemm2<<<GB, 256, 0, stream>>>(ab, w2t, as2, ad2, hb, als, ald);
  k_agg<<<NN / 4, 256, 0, stream>>>(hb, als, ald, rowptr, rec, 8, p2, b2, ab);

  // Pool + readout
  k_pool<<<GG, 256, 0, stream>>>(ab, batch, Wl, bl, out);
}

// Round 11
// 284.190 us; speedup vs baseline: 1.0874x; 1.0070x over previous
//
#include <hip/hip_runtime.h>
#include <math.h>

// Problem constants (fixed by reference)
static constexpr int NN = 50000;   // nodes
static constexpr int EE = 400000;  // edges (without self loops)
static constexpr int GG = 2048;    // graphs
static constexpr int TASKS = 12;

typedef __attribute__((ext_vector_type(8))) short short8;   // 8 bf16 (4 VGPRs)
typedef __attribute__((ext_vector_type(4))) float floatx4;  // MFMA acc

__device__ __forceinline__ unsigned short f2bf(float f) {
  unsigned u = __float_as_uint(f);
  u = u + 0x7fffu + ((u >> 16) & 1u);  // RNE
  return (unsigned short)(u >> 16);
}
__device__ __forceinline__ float bflo(unsigned u) { return __uint_as_float(u << 16); }
__device__ __forceinline__ float bfhi(unsigned u) { return __uint_as_float(u & 0xffff0000u); }

// ---------------------------------------------------------------------------
// Fused independent preamble, grid-partitioned:
//   [0,NBDEG)       in-degree histogram (distributed atomics — safe)
//   [+NBMEAN)       edge_attr mean sums (LDS pre-reduce, 6 atomics/blk — R5 lesson)
//   [+NBX)          x -> bf16 [NN][32] zero-padded (8 outputs/thread)
//   [+NW1)          W1 -> bf16 fragment-tiled [row>>4][kc][row&15][8], K=32
//   [+NW2)          W2 -> bf16 fragment-tiled [row>>4][kc][row&15][8], K=256
// Tiled layout makes each GEMM B-fragment load a contiguous 1KB wave burst
// (R9's B^T row-major gave 16 scattered 64B requests per load instr).
static constexpr int NBDEG = (EE + 255) / 256;     // 1563
static constexpr int NBMEAN = 256;
static constexpr int NBX = (NN * 4 + 255) / 256;   // 782 (thread = 8 bf16 outs)
static constexpr int NW1 = 32;
static constexpr int NW2 = 256;
__global__ void k_pre(const int* __restrict__ dst, const float* __restrict__ ea,
                      const float* __restrict__ x, const float* __restrict__ W1,
                      const float* __restrict__ W2, int* __restrict__ deg,
                      float* __restrict__ msum, unsigned short* __restrict__ xb,
                      unsigned short* __restrict__ w1t, unsigned short* __restrict__ w2t) {
  const int b = blockIdx.x;
  const int t = threadIdx.x;
  if (b < NBDEG) {
    int e = b * 256 + t;
    if (e < EE) atomicAdd(&deg[dst[e]], 1);
  } else if (b < NBDEG + NBMEAN) {
    float s[6] = {0, 0, 0, 0, 0, 0};
    for (int e = (b - NBDEG) * 256 + t; e < EE; e += NBMEAN * 256) {
#pragma unroll
      for (int d = 0; d < 6; d++) s[d] += ea[(size_t)e * 6 + d];
    }
    __shared__ float ls[6];
    if (t < 6) ls[t] = 0.f;
    __syncthreads();
#pragma unroll
    for (int d = 0; d < 6; d++) atomicAdd(&ls[d], s[d]);
    __syncthreads();
    if (t < 6) atomicAdd(&msum[t], ls[t]);
  } else if (b < NBDEG + NBMEAN + NBX) {
    int i = (b - NBDEG - NBMEAN) * 256 + t;  // i indexes 8-element chunks
    if (i < NN * 4) {
      int n = i >> 2, seg = i & 3;
      unsigned short v[8];
#pragma unroll
      for (int j = 0; j < 8; j++) {
        int k = seg * 8 + j;
        v[j] = (k < 29) ? f2bf(x[(size_t)n * 29 + k]) : (unsigned short)0;
      }
      *(short8*)(xb + (size_t)n * 32 + seg * 8) = *(short8*)v;
    }
  } else if (b < NBDEG + NBMEAN + NBX + NW1) {
    int i = (b - NBDEG - NBMEAN - NBX) * 256 + t;  // 8192 elems
    int row = i >> 5, k = i & 31;
    unsigned short v = (k < 29) ? f2bf(W1[(size_t)k * 256 + row]) : (unsigned short)0;
    w1t[((row >> 4) * 4 + (k >> 3)) * 128 + (row & 15) * 8 + (k & 7)] = v;
  } else {
    int i = (b - NBDEG - NBMEAN - NBX - NW1) * 256 + t;  // 65536 elems
    int row = i >> 8, k = i & 255;
    w2t[((row >> 4) * 32 + (k >> 3)) * 128 + (row & 15) * 8 + (k & 7)] = f2bf(W2[(size_t)k * 256 + row]);
  }
}

static constexpr int NBS = (NN + 255) / 256;  // 196 scan blocks

// block-level exclusive scan of deg -> rowptr (partial), block totals -> bsums.
// +2 trailing blocks compute per-layer edge params p1/p2 (consumed by the
// scatter partition of k_scatgemm1 and by k_agg's self-loop term).
__global__ void k_scan1(const int* __restrict__ deg, int* __restrict__ rowptr,
                        int* __restrict__ bsums, const float* __restrict__ We1,
                        const float* __restrict__ ae1, const float* __restrict__ We2,
                        const float* __restrict__ ae2, const float* __restrict__ msum,
                        float* __restrict__ p1, float* __restrict__ p2) {
  const int t = threadIdx.x;
  if (blockIdx.x >= NBS) {
    const int layer = blockIdx.x - NBS;
    const float* We = layer ? We2 : We1;
    const float* ae = layer ? ae2 : ae1;
    float* params = layer ? p2 : p1;
    __shared__ float vsh[24];
    if (t < 24) {
      int d = t >> 2, h = t & 3;
      float s = 0.f;
      for (int c = 0; c < 64; c++) s += We[d * 256 + h * 64 + c] * ae[h * 64 + c];
      vsh[t] = s;
      params[t] = s;
    }
    __syncthreads();
    if (t < 4) {
      float s = 0.f;
      const float invE = 1.0f / (float)EE;
#pragma unroll
      for (int d = 0; d < 6; d++) s += (msum[d] * invE) * vsh[d * 4 + t];
      params[24 + t] = s;
    }
    return;
  }
  __shared__ int sh[256];
  int i = blockIdx.x * 256 + t;
  int v = (i < NN) ? deg[i] : 0;
  sh[t] = v;
  __syncthreads();
  for (int off = 1; off < 256; off <<= 1) {
    int tv = (t >= off) ? sh[t - off] : 0;
    __syncthreads();
    sh[t] += tv;
    __syncthreads();
  }
  if (i < NN) rowptr[i] = sh[t] - v;  // exclusive within block
  if (t == 255) bsums[blockIdx.x] = sh[255];
}

// fused scan2+scan3: every block redundantly scans the 196 block sums,
// then applies its own block's exclusive prefix to rowptr.
__global__ void k_scan23(int* __restrict__ rowptr, const int* __restrict__ bsums, int nb) {
  __shared__ int sh[256];
  const int t = threadIdx.x;
  sh[t] = (t < nb) ? bsums[t] : 0;
  __syncthreads();
  for (int off = 1; off < 256; off <<= 1) {
    int tv = (t >= off) ? sh[t - off] : 0;
    __syncthreads();
    sh[t] += tv;  // inclusive scan
    __syncthreads();
  }
  const int add = (blockIdx.x == 0) ? 0 : sh[blockIdx.x - 1];
  int i = blockIdx.x * 256 + t;
  if (i < NN) rowptr[i] += add;
  if (i == 0) rowptr[NN] = EE;
}

// ---------------------------------------------------------------------------
// GEMM body (device fn): Y[M,256](bf16) = A[M,KP](bf16 row-major) @ B(tiled)
// + fused per-head logits. BM=64; 4 waves; wave w owns cols [64w,64w+64) = head w.
//
// R12: A tile staged in LDS, XOR-swizzled (one coalesced 4/32KB block read ->
// swizzled ds_write_b128; conflict-free ds_read_b128 frags).
//   swizzle f(o) = o ^ ((row(o)&7)<<4), row(o)=o/(2KP), same map write & read.
// R13: B register prefetch distance 2 (3 rolling buffers) + A frag LDS->reg
// prefetch distance 1.
// R19: staging reads clamped to A's valid range (last block previously
// over-read a few KB past A; clamped rows only feed discarded row>=M outputs).
template <int KP>
__device__ __forceinline__ void gemm_body(
    int bx, const unsigned short* __restrict__ A, const unsigned short* __restrict__ Bt,
    const float* __restrict__ a_s, const float* __restrict__ a_d,
    unsigned short* __restrict__ Y, float* __restrict__ als, float* __restrict__ ald, int M) {
  __shared__ __align__(16) unsigned short Ash[64 * KP];
  const int tid = threadIdx.x;
  const int lane = tid & 63;
  const int w = tid >> 6;
  const int l15 = lane & 15;
  const int quad = lane >> 4;
  const int row0 = bx * 64;

  // ---- stage A tile: coalesced clamped global read -> swizzled LDS write ----
  constexpr int STEPS = (64 * KP * 2) / (256 * 16);  // 1 (KP=32) or 8 (KP=256)
  {
    const size_t limit = (size_t)M * (KP * 2) - 16;  // last valid 16B read
    uint4 stg[STEPS];
#pragma unroll
    for (int s = 0; s < STEPS; s++) {
      size_t og = (size_t)row0 * (KP * 2) + s * 4096 + tid * 16;
      if (og > limit) og = limit;  // clamp: affects only discarded rows >= M
      stg[s] = *(const uint4*)((const char*)A + og);
    }
#pragma unroll
    for (int s = 0; s < STEPS; s++) {
      int o = s * 4096 + tid * 16;
      int row = o / (KP * 2);
      *(uint4*)((char*)Ash + (o ^ ((row & 7) << 4))) = stg[s];
    }
  }

  floatx4 acc[4][4];
#pragma unroll
  for (int i = 0; i < 4; i++)
#pragma unroll
    for (int j = 0; j < 4; j++) acc[i][j] = {0.f, 0.f, 0.f, 0.f};

  const unsigned short* pb[4];
#pragma unroll
  for (int j = 0; j < 4; j++)
    pb[j] = Bt + (size_t)((w * 4 + j) * (KP / 8) + quad) * 128 + l15 * 8;

  constexpr int NPH = KP / 32;
  short8 bfr[3][4];
#pragma unroll
  for (int j = 0; j < 4; j++) bfr[0][j] = *(const short8*)pb[j];  // overlaps staging
  if (NPH > 1) {
#pragma unroll
    for (int j = 0; j < 4; j++) {
      pb[j] += 512;  // 4 kc * 128
      bfr[1][j] = *(const short8*)pb[j];
    }
  }

  __syncthreads();

  // A fragment loader: conflict-free swizzled ds_read_b128 (row&7 == l15&7)
  auto ldA = [&](int ph, short8 (&dst)[4]) {
#pragma unroll
    for (int i = 0; i < 4; i++) {
      int lin = (i * 16 + l15) * (KP * 2) + ph * 64 + quad * 16;
      dst[i] = *(const short8*)((const char*)Ash + (lin ^ ((l15 & 7) << 4)));
    }
  };
  short8 af[2][4];
  ldA(0, af[0]);

#pragma unroll
  for (int ph = 0; ph < NPH; ph++) {
    if (ph + 2 < NPH) {  // B prefetch two phases ahead
#pragma unroll
      for (int j = 0; j < 4; j++) {
        pb[j] += 512;
        bfr[(ph + 2) % 3][j] = *(const short8*)pb[j];
      }
    }
    if (ph + 1 < NPH) ldA(ph + 1, af[(ph + 1) & 1]);  // A frag one ahead
#pragma unroll
    for (int i = 0; i < 4; i++)
#pragma unroll
      for (int j = 0; j < 4; j++)
        acc[i][j] = __builtin_amdgcn_mfma_f32_16x16x32_bf16(af[ph & 1][i], bfr[ph % 3][j], acc[i][j], 0, 0, 0);
  }
  // epilogue: C/D layout (m89) col = lane&15, row = (lane>>4)*4 + reg.
  float asc[4], adc[4];
#pragma unroll
  for (int j = 0; j < 4; j++) {
    asc[j] = a_s[w * 64 + j * 16 + l15];
    adc[j] = a_d[w * 64 + j * 16 + l15];
  }
#pragma unroll
  for (int i = 0; i < 4; i++) {
#pragma unroll
    for (int r = 0; r < 4; r++) {
      const int row = row0 + i * 16 + quad * 4 + r;
      unsigned ub[4];
      float hv[4];
#pragma unroll
      for (int j = 0; j < 4; j++) {
        ub[j] = f2bf(acc[i][j][r]);
        hv[j] = __uint_as_float(ub[j] << 16);  // dot uses rounded value (matches agg reads)
      }
      if (row < M) {
#pragma unroll
        for (int j = 0; j < 4; j++) Y[(size_t)row * 256 + w * 64 + j * 16 + l15] = (unsigned short)ub[j];
      }
      float ps = hv[0] * asc[0] + hv[1] * asc[1] + hv[2] * asc[2] + hv[3] * asc[3];
      float pd = hv[0] * adc[0] + hv[1] * adc[1] + hv[2] * adc[2] + hv[3] * adc[3];
#pragma unroll
      for (int off = 1; off < 16; off <<= 1) {
        ps += __shfl_xor(ps, off, 64);
        pd += __shfl_xor(pd, off, 64);
      }
      if (l15 == 0 && row < M) {
        als[row * 4 + w] = ps;
        ald[row * 4 + w] = pd;
      }
    }
  }
}

static constexpr int GB = (NN + 63) / 64;  // 782 GEMM blocks

// Fused: CSR scatter (1563 blks) ∥ layer-1 GEMM (782 blks).
// R18/R19: scatter computes BOTH layers' per-edge logit contributions AT
// SCATTER TIME (overlapping GEMM1's latency stalls — R3's winning trick) and
// writes ONE 64B line-aligned record
//   {src(bitcast), eid(bitcast), 0, 0, ed1[4], ed2[4], 0,0,0,0}
// with four ADJACENT float4 stores: exactly one fully-dirtied line per edge.
__global__ __launch_bounds__(256, 2) void k_scatgemm1(
    const int* __restrict__ ei, const int* __restrict__ rowptr, int* __restrict__ cursor,
    float* __restrict__ rec, const float* __restrict__ ea,
    const float* __restrict__ p1, const float* __restrict__ p2,
    const unsigned short* __restrict__ xb, const unsigned short* __restrict__ w1t,
    const float* __restrict__ as1, const float* __restrict__ ad1,
    unsigned short* __restrict__ hb, float* __restrict__ als, float* __restrict__ ald) {
  const int b = blockIdx.x;
  const int t = threadIdx.x;
  if (b < NBDEG) {
    int e = b * 256 + t;
    if (e >= EE) return;
    int s = ei[e];
    int d = ei[EE + e];
    int p = atomicAdd(&cursor[d], 1);
    int slot = rowptr[d] + p;
    // per-edge logit contributions, both layers (identical FMA order to R3/R5)
    const float* ep = ea + (size_t)e * 6;
    float2 e0 = *(const float2*)ep;
    float2 e1 = *(const float2*)(ep + 2);
    float2 e2 = *(const float2*)(ep + 4);
    float c1[4], c2[4];
#pragma unroll
    for (int h = 0; h < 4; h++) {
      c1[h] = e0.x * p1[0 * 4 + h] + e0.y * p1[1 * 4 + h] + e1.x * p1[2 * 4 + h] +
              e1.y * p1[3 * 4 + h] + e2.x * p1[4 * 4 + h] + e2.y * p1[5 * 4 + h];
      c2[h] = e0.x * p2[0 * 4 + h] + e0.y * p2[1 * 4 + h] + e1.x * p2[2 * 4 + h] +
              e1.y * p2[3 * 4 + h] + e2.x * p2[4 * 4 + h] + e2.y * p2[5 * 4 + h];
    }
    float* rp = rec + (size_t)slot * 16;  // 64B record, 64B-aligned
    *(float4*)rp = make_float4(__int_as_float(s), __int_as_float(e), 0.f, 0.f);
    *(float4*)(rp + 4) = make_float4(c1[0], c1[1], c1[2], c1[3]);
    *(float4*)(rp + 8) = make_float4(c2[0], c2[1], c2[2], c2[3]);
    *(float4*)(rp + 12) = make_float4(0.f, 0.f, 0.f, 0.f);  // full-line dirty
  } else {
    gemm_body<32>(b - NBDEG, xb, w1t, as1, ad1, hb, als, ald, NN);
  }
}

// layer-2 GEMM standalone (clean — R7 showed an edc rider here cost ~5µs:
// rider blocks inherit the kernel's 32KB static LDS and occupy full CU slots).
__global__ __launch_bounds__(256, 2) void k_gemm2(
    const unsigned short* __restrict__ A, const unsigned short* __restrict__ Bt,
    const float* __restrict__ a_s, const float* __restrict__ a_d,
    unsigned short* __restrict__ Y, float* __restrict__ als, float* __restrict__ ald) {
  gemm_body<256>(blockIdx.x, A, Bt, a_s, a_d, Y, als, ald, NN);
}

__device__ __forceinline__ float leaky02(float x) { return x > 0.f ? x : 0.2f * x; }

// GAT aggregation on bf16 h, one wave per node (per-node blocks — R17: block
// order must track address order). Halves of the wave own even/odd CSR slots;
// chunked 4-deep gather. R18: meta = one 64B record/slot (edoff selects layer).
// R20: LAYER-2 POOL FUSION — when pooled != nullptr the relu'd f32 output is
// NOT written to houtb (25.6MB saved) and k_pool's 25.6MB re-read dies too:
// the block reduces its 4 nodes' outputs by graph in LDS (batch sorted -> 1-2
// distinct graphs/block) and atomicAdds 256 floats per distinct graph into
// pooled[G][256] (~3.7M f32 atomics total, device-scope). Pool now sums
// UNROUNDED f32 h — closer to the f32 reference than the old bf16-rounded sum.
// Grid is exactly NN/4 (NN divisible by 4) so every wave owns a valid node —
// no early-out, __syncthreads is uniform.
__global__ __launch_bounds__(256) void k_agg(
    const unsigned short* __restrict__ hinb, const float* __restrict__ als,
    const float* __restrict__ ald, const int* __restrict__ rowptr, const float* __restrict__ rec,
    int edoff, const float* __restrict__ params, const float* __restrict__ bias,
    unsigned short* __restrict__ houtb, const int* __restrict__ batch,
    float* __restrict__ pooled) {
  __shared__ float lout[4][32][8];
  __shared__ int lgs[4];
  const int lane = threadIdx.x & 63;
  const int wv = threadIdx.x >> 6;
  const int n = blockIdx.x * 4 + wv;  // always < NN (grid = NN/4 exact)
  const int half = lane >> 5;  // 0: even slots, 1: odd slots
  const int sl = lane & 31;    // 16B chunk (8 channels) within row
  const int head = sl >> 3;

  const float aldn = ald[n * 4 + head];
  float acc[8];
  float ssum;
  {
    float slg = leaky02(als[n * 4 + head] + aldn + params[24 + head]);
    float exs = __expf(slg);
    float wgt = (half == 0) ? exs : 0.f;  // self term counted once (cross-half merge later)
    ssum = wgt;
    uint4 uv = *(const uint4*)(hinb + (size_t)n * 256 + sl * 8);
    acc[0] = bflo(uv.x) * wgt;
    acc[1] = bfhi(uv.x) * wgt;
    acc[2] = bflo(uv.y) * wgt;
    acc[3] = bfhi(uv.y) * wgt;
    acc[4] = bflo(uv.z) * wgt;
    acc[5] = bfhi(uv.z) * wgt;
    acc[6] = bflo(uv.w) * wgt;
    acc[7] = bfhi(uv.w) * wgt;
  }
  const int end = rowptr[n + 1];
  int s = rowptr[n] + half;
  while (s < end) {
    int sid[4];
    float edv[4];
    // meta for 4 slots — one broadcast 64B line each (sequential in slot order)
#pragma unroll
    for (int k = 0; k < 4; k++) {
      const int q = s + 2 * k;
      const bool v = q < end;           // uniform across the 32-lane half
      const int idx = v ? q : end - 1;  // clamped: valid address
      const float* rp = rec + (size_t)idx * 16;
      sid[k] = __float_as_int(rp[0]);
      edv[k] = v ? rp[edoff + head] : 0.f;
    }
    // src-logit + h-row gathers, all in flight together
    float alv[4];
#pragma unroll
    for (int k = 0; k < 4; k++) alv[k] = als[(size_t)sid[k] * 4 + head];
    uint4 r[4];
#pragma unroll
    for (int k = 0; k < 4; k++) {
      r[k] = make_uint4(0u, 0u, 0u, 0u);
      if (s + 2 * k < end) r[k] = *(const uint4*)(hinb + (size_t)sid[k] * 256 + sl * 8);
    }
#pragma unroll
    for (int k = 0; k < 4; k++) {
      const float ex = (s + 2 * k < end) ? __expf(leaky02(alv[k] + aldn + edv[k])) : 0.f;
      acc[0] += bflo(r[k].x) * ex;
      acc[1] += bfhi(r[k].x) * ex;
      acc[2] += bflo(r[k].y) * ex;
      acc[3] += bfhi(r[k].y) * ex;
      acc[4] += bflo(r[k].z) * ex;
      acc[5] += bfhi(r[k].z) * ex;
      acc[6] += bflo(r[k].w) * ex;
      acc[7] += bfhi(r[k].w) * ex;
      ssum += ex;
    }
    s += 8;  // 4 slots per half per chunk
  }
  // merge even/odd halves (same channel set lives at lane and lane^32)
#pragma unroll
  for (int j = 0; j < 8; j++) acc[j] += __shfl_xor(acc[j], 32, 64);
  ssum += __shfl_xor(ssum, 32, 64);

  if (pooled == nullptr) {
    // layer-1: relu -> bf16 row for the next GEMM
    if (half == 0) {
      const float inv = 1.f / (ssum + 1e-16f);
      float4 b0 = *(const float4*)(bias + sl * 8);
      float4 b1 = *(const float4*)(bias + sl * 8 + 4);
      const float bb[8] = {b0.x, b0.y, b0.z, b0.w, b1.x, b1.y, b1.z, b1.w};
      uint p[4];
#pragma unroll
      for (int j = 0; j < 4; j++) {
        float e0 = fmaxf(acc[2 * j] * inv + bb[2 * j], 0.f);
        float e1 = fmaxf(acc[2 * j + 1] * inv + bb[2 * j + 1], 0.f);
        p[j] = (uint)f2bf(e0) | ((uint)f2bf(e1) << 16);
      }
      *(uint4*)(houtb + (size_t)n * 256 + sl * 8) = make_uint4(p[0], p[1], p[2], p[3]);
    }
  } else {
    // layer-2: reduce by graph within the block, atomicAdd into pooled
    if (lane == 0) lgs[wv] = batch[n];
    if (half == 0) {
      const float inv = 1.f / (ssum + 1e-16f);
      float4 b0 = *(const float4*)(bias + sl * 8);
      float4 b1 = *(const float4*)(bias + sl * 8 + 4);
      const float bb[8] = {b0.x, b0.y, b0.z, b0.w, b1.x, b1.y, b1.z, b1.w};
#pragma unroll
      for (int j = 0; j < 8; j++) lout[wv][sl][j] = fmaxf(acc[j] * inv + bb[j], 0.f);
    }
    __syncthreads();
    const int t = threadIdx.x;  // channel c = t
    int w0 = 0;
    while (w0 < 4) {  // lgs uniform across block -> no divergence
      const int gc = lgs[w0];
      float sum = 0.f;
      int w = w0;
      for (; w < 4 && lgs[w] == gc; w++) sum += lout[w][t >> 3][t & 7];
      atomicAdd(&pooled[(size_t)gc * 256 + t], sum);
      w0 = w;
    }
  }
}

// R20: tiny readout — pooled[G][256] f32 sums -> mean -> 256x12 linear.
// Replaces k_pool's full 25.6MB re-read of ab.
__global__ __launch_bounds__(64) void k_readout(const float* __restrict__ pooled,
                                                const int* __restrict__ batch,
                                                const float* __restrict__ Wl,
                                                const float* __restrict__ bl,
                                                float* __restrict__ out) {
  int g = blockIdx.x;
  int t = threadIdx.x;
  int lo = 0, hi = NN;
  while (lo < hi) {
    int mid = (lo + hi) >> 1;
    if (batch[mid] < g) lo = mid + 1; else hi = mid;
  }
  int start = lo;
  hi = NN;
  while (lo < hi) {
    int mid = (lo + hi) >> 1;
    if (batch[mid] < g + 1) lo = mid + 1; else hi = mid;
  }
  int cnt = lo - start;
  if (t < TASKS) {
    float invc = 1.f / fmaxf((float)cnt, 1.f);
    float o = bl[t];
    const float* pg = pooled + (size_t)g * 256;
    for (int c = 0; c < 256; c++) o += pg[c] * invc * Wl[c * 12 + t];
    out[(size_t)g * 12 + t] = o;
  }
}

// ---------------------------------------------------------------------------
extern "C" void kernel_launch(void* const* d_in, const int* in_sizes, int n_in,
                              void* d_out, int out_size, void* d_ws, size_t ws_size,
                              hipStream_t stream) {
  const float* x = (const float*)d_in[0];
  const int* ei = (const int*)d_in[1];
  const float* ea = (const float*)d_in[2];
  const int* batch = (const int*)d_in[3];
  const float* W1 = (const float*)d_in[4];
  const float* as1 = (const float*)d_in[5];
  const float* ad1 = (const float*)d_in[6];
  const float* We1 = (const float*)d_in[7];
  const float* ae1 = (const float*)d_in[8];
  const float* b1 = (const float*)d_in[9];
  const float* W2 = (const float*)d_in[10];
  const float* as2 = (const float*)d_in[11];
  const float* ad2 = (const float*)d_in[12];
  const float* We2 = (const float*)d_in[13];
  const float* ae2 = (const float*)d_in[14];
  const float* b2 = (const float*)d_in[15];
  const float* Wl = (const float*)d_in[16];
  const float* bl = (const float*)d_in[17];
  float* out = (float*)d_out;

  // workspace carve-up (256B aligned)
  char* ws = (char*)d_ws;
  size_t off = 0;
  auto take = [&](size_t bytes) -> char* {
    char* p = ws + off;
    off = (off + bytes + 255) & ~(size_t)255;
    return p;
  };
  float* msum = (float*)take(8 * 4);
  int* deg = (int*)take((size_t)NN * 4);
  int* cursor = (int*)take((size_t)NN * 4);
  float* pooled = (float*)take((size_t)GG * 256 * 4);  // 2MB, zeroed
  size_t zero_end = off;  // msum+deg+cursor+pooled need zeroing
  int* rowptr = (int*)take((size_t)(NN + 1) * 4);
  int* bsums = (int*)take(256 * 4);
  float* rec = (float*)take((size_t)EE * 64);  // 64B/edge combined record
  float* p1 = (float*)take(32 * 4);
  float* p2 = (float*)take(32 * 4);
  float* als = (float*)take((size_t)NN * 4 * 4);
  float* ald = (float*)take((size_t)NN * 4 * 4);
  unsigned short* hb = (unsigned short*)take((size_t)NN * 256 * 2);  // GEMM out (bf16)
  unsigned short* ab = (unsigned short*)take((size_t)NN * 256 * 2);  // agg out (bf16)
  unsigned short* xb = (unsigned short*)take((size_t)NN * 32 * 2);
  unsigned short* w1t = (unsigned short*)take((size_t)256 * 32 * 2);
  unsigned short* w2t = (unsigned short*)take((size_t)256 * 256 * 2);
  (void)ws_size;

  hipMemsetAsync(ws, 0, zero_end, stream);

  k_pre<<<NBDEG + NBMEAN + NBX + NW1 + NW2, 256, 0, stream>>>(ei + EE, ea, x, W1, W2,
                                                              deg, msum, xb, w1t, w2t);
  k_scan1<<<NBS + 2, 256, 0, stream>>>(deg, rowptr, bsums, We1, ae1, We2, ae2, msum, p1, p2);
  k_scan23<<<NBS, 256, 0, stream>>>(rowptr, bsums, NBS);

  // CSR scatter (with both layers' edc, one 64B line/edge) ∥ layer-1 GEMM
  k_scatgemm1<<<NBDEG + GB, 256, 0, stream>>>(ei, rowptr, cursor, rec, ea, p1, p2,
                                              xb, w1t, as1, ad1, hb, als, ald);

  // Layer 1 (cont.)
  k_agg<<<NN / 4, 256, 0, stream>>>(hb, als, ald, rowptr, rec, 4, p1, b1, ab,
                                    batch, nullptr);

  // Layer 2 (agg fuses the graph-pool: no ab write, atomics into pooled)
  k_gemm2<<<GB, 256, 0, stream>>>(ab, w2t, as2, ad2, hb, als, ald);
  k_agg<<<NN / 4, 256, 0, stream>>>(hb, als, ald, rowptr, rec, 8, p2, b2, ab,
                                    batch, pooled);

  // Readout (256 -> 12 linear on pooled means)
  k_readout<<<GG, 64, 0, stream>>>(pooled, batch, Wl, bl, out);
}